// Round 1
// baseline (3058.556 us; speedup 1.0000x reference)
//
#include <hip/hip_runtime.h>

#define BN_EPS 1e-5f

// ---------------------------------------------------------------- degree
__global__ __launch_bounds__(256) void deg_kernel(const int* __restrict__ dst,
                                                  float* __restrict__ deg, int E) {
  int e = blockIdx.x * 256 + threadIdx.x;
  if (e < E) atomicAdd(&deg[dst[e]], 1.0f);
}

// ------------------------------------------------------- scatter-add (mean numerator)
// thread t = (edge e, float4-chunk c). 25 (F=100) or 32 (F=128) chunks/edge.
template<int F>
__global__ __launch_bounds__(256) void scatter_kernel(const float* __restrict__ feat,
    const int* __restrict__ src, const int* __restrict__ dst,
    float* __restrict__ agg, int E) {
  const int CH = F / 4;
  int t = blockIdx.x * 256 + threadIdx.x;
  if (t >= E * CH) return;
  int e = t / CH;
  int c = t - e * CH;
  int s = src[e], d = dst[e];
  float4 v = *(const float4*)(feat + (size_t)s * F + (size_t)c * 4);
  float* o = agg + (size_t)d * F + (size_t)c * 4;
  atomicAdd(o + 0, v.x);
  atomicAdd(o + 1, v.y);
  atomicAdd(o + 2, v.z);
  atomicAdd(o + 3, v.w);
}

// ------------------------------------------------ SAGE layer: relu(mean@Wl + bl + x@Wr)
// Block: 128 threads (one per output col), TILE=16 nodes per block.
template<int K>
__global__ __launch_bounds__(128) void sage_kernel(
    const float* __restrict__ agg, const float* __restrict__ xin,
    const float* __restrict__ deg,
    const float* __restrict__ Wl, const float* __restrict__ bl,
    const float* __restrict__ Wr, float* __restrict__ out, int N) {
  const int TILE = 16;
  __shared__ float sm[TILE][K];   // mean-aggregated neighbor features
  __shared__ float sx[TILE][K];   // self features
  __shared__ float sinv[TILE];
  int j = threadIdx.x;            // output column 0..127
  int n0 = blockIdx.x * TILE;

  if (j < TILE) {
    int node = n0 + j;
    float d = (node < N) ? deg[node] : 1.0f;
    sinv[j] = 1.0f / fmaxf(d, 1.0f);
  }
  __syncthreads();

  for (int idx = j; idx < TILE * K; idx += 128) {
    int n = idx / K;
    int k = idx - n * K;
    int node = n0 + n;
    if (node < N) {
      sm[n][k] = agg[(size_t)node * K + k] * sinv[n];
      sx[n][k] = xin[(size_t)node * K + k];
    } else {
      sm[n][k] = 0.0f;
      sx[n][k] = 0.0f;
    }
  }
  __syncthreads();

  float acc[TILE];
  float b = bl[j];
#pragma unroll
  for (int n = 0; n < TILE; ++n) acc[n] = b;

  for (int k0 = 0; k0 < K; k0 += 4) {
    float wl0 = Wl[(k0 + 0) * 128 + j];
    float wl1 = Wl[(k0 + 1) * 128 + j];
    float wl2 = Wl[(k0 + 2) * 128 + j];
    float wl3 = Wl[(k0 + 3) * 128 + j];
    float wr0 = Wr[(k0 + 0) * 128 + j];
    float wr1 = Wr[(k0 + 1) * 128 + j];
    float wr2 = Wr[(k0 + 2) * 128 + j];
    float wr3 = Wr[(k0 + 3) * 128 + j];
#pragma unroll
    for (int n = 0; n < TILE; ++n) {
      float4 a = *(const float4*)&sm[n][k0];
      float4 x4 = *(const float4*)&sx[n][k0];
      acc[n] += a.x * wl0 + a.y * wl1 + a.z * wl2 + a.w * wl3
              + x4.x * wr0 + x4.y * wr1 + x4.z * wr2 + x4.w * wr3;
    }
  }

  int lim = N - n0;
#pragma unroll
  for (int n = 0; n < TILE; ++n) {
    if (n < lim) out[(size_t)(n0 + n) * 128 + j] = fmaxf(acc[n], 0.0f);
  }
}

// ------------------------------------------------------------ plain GEMM + bias
template<int K, int COLS>
__global__ __launch_bounds__(COLS) void gemm_kernel(
    const float* __restrict__ A, const float* __restrict__ W,
    const float* __restrict__ bias, float* __restrict__ out, int N) {
  const int TILE = 16;
  __shared__ float sa[TILE][K];
  int j = threadIdx.x;
  int n0 = blockIdx.x * TILE;

  for (int idx = j; idx < TILE * K; idx += COLS) {
    int n = idx / K;
    int k = idx - n * K;
    int node = n0 + n;
    sa[n][k] = (node < N) ? A[(size_t)node * K + k] : 0.0f;
  }
  __syncthreads();

  float acc[TILE];
  float b = bias[j];
#pragma unroll
  for (int n = 0; n < TILE; ++n) acc[n] = b;

  for (int k0 = 0; k0 < K; k0 += 4) {
    float w0 = W[(k0 + 0) * COLS + j];
    float w1 = W[(k0 + 1) * COLS + j];
    float w2 = W[(k0 + 2) * COLS + j];
    float w3 = W[(k0 + 3) * COLS + j];
#pragma unroll
    for (int n = 0; n < TILE; ++n) {
      float4 a = *(const float4*)&sa[n][k0];
      acc[n] += a.x * w0 + a.y * w1 + a.z * w2 + a.w * w3;
    }
  }

  int lim = N - n0;
#pragma unroll
  for (int n = 0; n < TILE; ++n) {
    if (n < lim) out[(size_t)(n0 + n) * COLS + j] = acc[n];
  }
}

// ------------------------------------------------------- per-column sum / sumsq
__global__ __launch_bounds__(256) void colstats_kernel(const float* __restrict__ y,
    int N, int C, float* __restrict__ sum, float* __restrict__ sumsq) {
  int tid = blockIdx.x * 256 + threadIdx.x;
  int total = gridDim.x * 256;
  int col = tid % C;
  int row0 = tid / C;
  int stride = total / C;
  float s = 0.0f, ss = 0.0f;
  for (int r = row0; r < N; r += stride) {
    float v = y[(size_t)r * C + col];
    s += v;
    ss += v * v;
  }
  atomicAdd(&sum[col], s);
  atomicAdd(&sumsq[col], ss);
}

// ------------------------------------------------------------- BN (train) + ReLU, in-place
__global__ __launch_bounds__(256) void bn_relu_kernel(float* __restrict__ y,
    int N, int C, const float* __restrict__ sum, const float* __restrict__ sumsq,
    const float* __restrict__ g, const float* __restrict__ be) {
  int t = blockIdx.x * 256 + threadIdx.x;
  if (t >= N * C) return;
  int col = t % C;
  float invN = 1.0f / (float)N;
  float m = sum[col] * invN;
  float v = sumsq[col] * invN - m * m;
  float val = (y[t] - m) * rsqrtf(v + BN_EPS) * g[col] + be[col];
  y[t] = fmaxf(val, 0.0f);
}

// ------------------------------------------------------------- final head: z @ W3 + b3
__global__ __launch_bounds__(256) void final_kernel(const float* __restrict__ z,
    const float* __restrict__ W3, const float* __restrict__ b3,
    float* __restrict__ out, int N) {
  int wave = threadIdx.x >> 6;            // 4 waves/block
  int lane = threadIdx.x & 63;
  int i = blockIdx.x * 4 + wave;
  if (i >= N) return;
  float v = z[(size_t)i * 64 + lane] * W3[lane];
#pragma unroll
  for (int off = 32; off > 0; off >>= 1) v += __shfl_down(v, off);
  if (lane == 0) out[i] = v + b3[0];
}

// ================================================================ launch
extern "C" void kernel_launch(void* const* d_in, const int* in_sizes, int n_in,
                              void* d_out, int out_size, void* d_ws, size_t ws_size,
                              hipStream_t stream) {
  const int F = 100, H = 128, H2 = 64;
  const int N = in_sizes[0] / F;
  const int E = in_sizes[1] / 2;

  const float* x   = (const float*)d_in[0];
  const int* edge  = (const int*)d_in[1];
  const int* src   = edge;
  const int* dst   = edge + E;
  const float* Wl1 = (const float*)d_in[2];
  const float* bl1 = (const float*)d_in[3];
  const float* Wr1 = (const float*)d_in[4];
  const float* Wl2 = (const float*)d_in[5];
  const float* bl2 = (const float*)d_in[6];
  const float* Wr2 = (const float*)d_in[7];
  const float* W1  = (const float*)d_in[8];
  const float* b1  = (const float*)d_in[9];
  const float* g1  = (const float*)d_in[10];
  const float* be1 = (const float*)d_in[11];
  const float* W2  = (const float*)d_in[12];
  const float* b2  = (const float*)d_in[13];
  const float* g2  = (const float*)d_in[14];
  const float* be2 = (const float*)d_in[15];
  const float* W3  = (const float*)d_in[16];
  const float* b3  = (const float*)d_in[17];

  float* out0 = (float*)d_out;              // [N]
  float* h1   = out0 + N;                   // [N,128]
  float* h2   = h1 + (size_t)N * H;         // [N,128]

  float* ws    = (float*)d_ws;
  float* deg   = ws;                        // [N]
  float* sum1  = ws + N;                    // [128]
  float* sq1   = sum1 + 128;                // [128]
  float* sum2  = sq1 + 128;                 // [64]
  float* sq2   = sum2 + 64;                 // [64]
  float* bufA  = ws + N + 384;              // [N,128]
  float* bufB  = bufA + (size_t)N * 128;    // [N,64]

  // ---- zero-init scratch (ws is poisoned 0xAA each call)
  hipMemsetAsync(deg, 0, (size_t)N * sizeof(float), stream);
  hipMemsetAsync(sum1, 0, 384 * sizeof(float), stream);
  hipMemsetAsync(bufA, 0, (size_t)N * 128 * sizeof(float), stream);

  // ---- degree
  deg_kernel<<<(E + 255) / 256, 256, 0, stream>>>(dst, deg, E);

  // ---- layer 1: aggregate x, SAGE conv, ReLU -> h1
  {
    int nthreads = E * (F / 4);
    scatter_kernel<100><<<(nthreads + 255) / 256, 256, 0, stream>>>(x, src, dst, bufA, E);
    sage_kernel<100><<<(N + 15) / 16, 128, 0, stream>>>(bufA, x, deg, Wl1, bl1, Wr1, h1, N);
  }

  // ---- layer 2: aggregate h1, SAGE conv, ReLU -> h2
  hipMemsetAsync(bufA, 0, (size_t)N * 128 * sizeof(float), stream);
  {
    int nthreads = E * (H / 4);
    scatter_kernel<128><<<(nthreads + 255) / 256, 256, 0, stream>>>(h1, src, dst, bufA, E);
    sage_kernel<128><<<(N + 15) / 16, 128, 0, stream>>>(bufA, h1, deg, Wl2, bl2, Wr2, h2, N);
  }

  // ---- MLP layer 1: y1 = h2 @ W1 + b1 ; BN ; ReLU  (in bufA)
  gemm_kernel<128, 128><<<(N + 15) / 16, 128, 0, stream>>>(h2, W1, b1, bufA, N);
  colstats_kernel<<<240, 256, 0, stream>>>(bufA, N, 128, sum1, sq1);
  bn_relu_kernel<<<((size_t)N * 128 + 255) / 256, 256, 0, stream>>>(bufA, N, 128, sum1, sq1, g1, be1);

  // ---- MLP layer 2: y2 = z1 @ W2 + b2 ; BN ; ReLU  (in bufB)
  gemm_kernel<128, 64><<<(N + 15) / 16, 64, 0, stream>>>(bufA, W2, b2, bufB, N);
  colstats_kernel<<<240, 256, 0, stream>>>(bufB, N, 64, sum2, sq2);
  bn_relu_kernel<<<((size_t)N * 64 + 255) / 256, 256, 0, stream>>>(bufB, N, 64, sum2, sq2, g2, be2);

  // ---- head: out = z2 @ W3 + b3
  final_kernel<<<(N + 3) / 4, 256, 0, stream>>>(bufB, W3, b3, out0, N);
}

// Round 2
// 798.304 us; speedup vs baseline: 3.8313x; 3.8313x over previous
//
#include <hip/hip_runtime.h>

#define BN_EPS 1e-5f

// ---------------------------------------------------------------- degree histogram (int)
__global__ __launch_bounds__(256) void deg_kernel(const int* __restrict__ dst,
                                                  int* __restrict__ deg, int E) {
  int e = blockIdx.x * 256 + threadIdx.x;
  if (e < E) atomicAdd(&deg[dst[e]], 1);
}

// ---------------------------------------------------------------- exclusive scan (1 block)
__global__ __launch_bounds__(1024) void scan_kernel(const int* __restrict__ deg,
                                                    int* __restrict__ row_start, int N) {
  __shared__ int partial[1024];
  int tid = threadIdx.x;
  int chunk = (N + 1023) / 1024;
  int base = tid * chunk;
  int s = 0;
  for (int i = 0; i < chunk; ++i) {
    int idx = base + i;
    if (idx < N) s += deg[idx];
  }
  partial[tid] = s;
  __syncthreads();
  for (int d = 1; d < 1024; d <<= 1) {
    int t = (tid >= d) ? partial[tid - d] : 0;
    __syncthreads();
    partial[tid] += t;
    __syncthreads();
  }
  int off = (tid == 0) ? 0 : partial[tid - 1];
  for (int i = 0; i < chunk; ++i) {
    int idx = base + i;
    if (idx < N) { row_start[idx] = off; off += deg[idx]; }
  }
}

// ---------------------------------------------------------------- CSR fill
__global__ __launch_bounds__(256) void fill_kernel(const int* __restrict__ src,
    const int* __restrict__ dst, int* __restrict__ cursor,
    int* __restrict__ eidx, int E) {
  int e = blockIdx.x * 256 + threadIdx.x;
  if (e >= E) return;
  int p = atomicAdd(&cursor[dst[e]], 1);
  eidx[p] = src[e];
}

// ---------------------------------------------------------------- gather mean (1 wave/node)
template<int F>
__global__ __launch_bounds__(256) void gather_mean_kernel(
    const float* __restrict__ feat, const int* __restrict__ eidx,
    const int* __restrict__ row_start, const int* __restrict__ deg,
    float* __restrict__ mean_out, int N) {
  int wave = threadIdx.x >> 6;
  int lane = threadIdx.x & 63;
  int node = blockIdx.x * 4 + wave;
  if (node >= N) return;
  int beg = row_start[node];
  int d = deg[node];
  float acc0 = 0.0f, acc1 = 0.0f;
  for (int i = 0; i < d; ++i) {
    int s = eidx[beg + i];
    const float* p = feat + (size_t)s * F;
    acc0 += p[lane];
    if (lane + 64 < F) acc1 += p[lane + 64];
  }
  float inv = 1.0f / fmaxf((float)d, 1.0f);
  float* o = mean_out + (size_t)node * F;
  o[lane] = acc0 * inv;
  if (lane + 64 < F) o[lane + 64] = acc1 * inv;
}

// ------------------------------------------------ SAGE layer: relu(mean@Wl + bl + x@Wr)
// Block: 128 threads (one per output col), TILE=16 nodes per block.
template<int K>
__global__ __launch_bounds__(128) void sage_kernel(
    const float* __restrict__ mean_in, const float* __restrict__ xin,
    const float* __restrict__ Wl, const float* __restrict__ bl,
    const float* __restrict__ Wr, float* __restrict__ out, int N) {
  const int TILE = 16;
  __shared__ float sm[TILE][K];   // mean-aggregated neighbor features
  __shared__ float sx[TILE][K];   // self features
  int j = threadIdx.x;            // output column 0..127
  int n0 = blockIdx.x * TILE;

  for (int idx = j; idx < TILE * K; idx += 128) {
    int n = idx / K;
    int k = idx - n * K;
    int node = n0 + n;
    if (node < N) {
      sm[n][k] = mean_in[(size_t)node * K + k];
      sx[n][k] = xin[(size_t)node * K + k];
    } else {
      sm[n][k] = 0.0f;
      sx[n][k] = 0.0f;
    }
  }
  __syncthreads();

  float acc[TILE];
  float b = bl[j];
#pragma unroll
  for (int n = 0; n < TILE; ++n) acc[n] = b;

  for (int k0 = 0; k0 < K; k0 += 4) {
    float wl0 = Wl[(k0 + 0) * 128 + j];
    float wl1 = Wl[(k0 + 1) * 128 + j];
    float wl2 = Wl[(k0 + 2) * 128 + j];
    float wl3 = Wl[(k0 + 3) * 128 + j];
    float wr0 = Wr[(k0 + 0) * 128 + j];
    float wr1 = Wr[(k0 + 1) * 128 + j];
    float wr2 = Wr[(k0 + 2) * 128 + j];
    float wr3 = Wr[(k0 + 3) * 128 + j];
#pragma unroll
    for (int n = 0; n < TILE; ++n) {
      float4 a = *(const float4*)&sm[n][k0];
      float4 x4 = *(const float4*)&sx[n][k0];
      acc[n] += a.x * wl0 + a.y * wl1 + a.z * wl2 + a.w * wl3
              + x4.x * wr0 + x4.y * wr1 + x4.z * wr2 + x4.w * wr3;
    }
  }

  int lim = N - n0;
#pragma unroll
  for (int n = 0; n < TILE; ++n) {
    if (n < lim) out[(size_t)(n0 + n) * 128 + j] = fmaxf(acc[n], 0.0f);
  }
}

// ------------------------------------------------------------ plain GEMM + bias
template<int K, int COLS>
__global__ __launch_bounds__(COLS) void gemm_kernel(
    const float* __restrict__ A, const float* __restrict__ W,
    const float* __restrict__ bias, float* __restrict__ out, int N) {
  const int TILE = 16;
  __shared__ float sa[TILE][K];
  int j = threadIdx.x;
  int n0 = blockIdx.x * TILE;

  for (int idx = j; idx < TILE * K; idx += COLS) {
    int n = idx / K;
    int k = idx - n * K;
    int node = n0 + n;
    sa[n][k] = (node < N) ? A[(size_t)node * K + k] : 0.0f;
  }
  __syncthreads();

  float acc[TILE];
  float b = bias[j];
#pragma unroll
  for (int n = 0; n < TILE; ++n) acc[n] = b;

  for (int k0 = 0; k0 < K; k0 += 4) {
    float w0 = W[(k0 + 0) * COLS + j];
    float w1 = W[(k0 + 1) * COLS + j];
    float w2 = W[(k0 + 2) * COLS + j];
    float w3 = W[(k0 + 3) * COLS + j];
#pragma unroll
    for (int n = 0; n < TILE; ++n) {
      float4 a = *(const float4*)&sa[n][k0];
      acc[n] += a.x * w0 + a.y * w1 + a.z * w2 + a.w * w3;
    }
  }

  int lim = N - n0;
#pragma unroll
  for (int n = 0; n < TILE; ++n) {
    if (n < lim) out[(size_t)(n0 + n) * COLS + j] = acc[n];
  }
}

// ------------------------------------------------------- per-column sum / sumsq
__global__ __launch_bounds__(256) void colstats_kernel(const float* __restrict__ y,
    int N, int C, float* __restrict__ sum, float* __restrict__ sumsq) {
  int tid = blockIdx.x * 256 + threadIdx.x;
  int total = gridDim.x * 256;
  int col = tid % C;
  int row0 = tid / C;
  int stride = total / C;
  float s = 0.0f, ss = 0.0f;
  for (int r = row0; r < N; r += stride) {
    float v = y[(size_t)r * C + col];
    s += v;
    ss += v * v;
  }
  atomicAdd(&sum[col], s);
  atomicAdd(&sumsq[col], ss);
}

// ------------------------------------------------------------- BN (train) + ReLU, in-place
__global__ __launch_bounds__(256) void bn_relu_kernel(float* __restrict__ y,
    int N, int C, const float* __restrict__ sum, const float* __restrict__ sumsq,
    const float* __restrict__ g, const float* __restrict__ be) {
  int t = blockIdx.x * 256 + threadIdx.x;
  if (t >= N * C) return;
  int col = t % C;
  float invN = 1.0f / (float)N;
  float m = sum[col] * invN;
  float v = sumsq[col] * invN - m * m;
  float val = (y[t] - m) * rsqrtf(v + BN_EPS) * g[col] + be[col];
  y[t] = fmaxf(val, 0.0f);
}

// ------------------------------------------------------------- final head: z @ W3 + b3
__global__ __launch_bounds__(256) void final_kernel(const float* __restrict__ z,
    const float* __restrict__ W3, const float* __restrict__ b3,
    float* __restrict__ out, int N) {
  int wave = threadIdx.x >> 6;            // 4 waves/block
  int lane = threadIdx.x & 63;
  int i = blockIdx.x * 4 + wave;
  if (i >= N) return;
  float v = z[(size_t)i * 64 + lane] * W3[lane];
#pragma unroll
  for (int off = 32; off > 0; off >>= 1) v += __shfl_down(v, off);
  if (lane == 0) out[i] = v + b3[0];
}

// ================================================================ launch
extern "C" void kernel_launch(void* const* d_in, const int* in_sizes, int n_in,
                              void* d_out, int out_size, void* d_ws, size_t ws_size,
                              hipStream_t stream) {
  const int F = 100, H = 128;
  const int N = in_sizes[0] / F;
  const int E = in_sizes[1] / 2;

  const float* x   = (const float*)d_in[0];
  const int* edge  = (const int*)d_in[1];
  const int* src   = edge;
  const int* dst   = edge + E;
  const float* Wl1 = (const float*)d_in[2];
  const float* bl1 = (const float*)d_in[3];
  const float* Wr1 = (const float*)d_in[4];
  const float* Wl2 = (const float*)d_in[5];
  const float* bl2 = (const float*)d_in[6];
  const float* Wr2 = (const float*)d_in[7];
  const float* W1  = (const float*)d_in[8];
  const float* b1  = (const float*)d_in[9];
  const float* g1  = (const float*)d_in[10];
  const float* be1 = (const float*)d_in[11];
  const float* W2  = (const float*)d_in[12];
  const float* b2  = (const float*)d_in[13];
  const float* g2  = (const float*)d_in[14];
  const float* be2 = (const float*)d_in[15];
  const float* W3  = (const float*)d_in[16];
  const float* b3  = (const float*)d_in[17];

  float* out0 = (float*)d_out;              // [N]
  float* h1   = out0 + N;                   // [N,128]
  float* h2   = h1 + (size_t)N * H;         // [N,128]

  // ---- workspace layout
  char* wsp = (char*)d_ws;
  int* deg       = (int*)wsp;                       wsp += (size_t)N * sizeof(int);
  int* row_start = (int*)wsp;                       wsp += (size_t)N * sizeof(int);
  int* cursor    = (int*)wsp;                       wsp += (size_t)N * sizeof(int);
  int* eidx      = (int*)wsp;                       wsp += (size_t)E * sizeof(int);
  float* sum1    = (float*)wsp;                     wsp += 128 * sizeof(float);
  float* sq1     = (float*)wsp;                     wsp += 128 * sizeof(float);
  float* sum2    = (float*)wsp;                     wsp += 64 * sizeof(float);
  float* sq2     = (float*)wsp;                     wsp += 64 * sizeof(float);
  float* bufA    = (float*)wsp;                     wsp += (size_t)N * 128 * sizeof(float);
  float* bufB    = (float*)wsp;

  // ---- zero-init the accumulated scratch (ws is poisoned 0xAA each call)
  hipMemsetAsync(deg, 0, (size_t)N * sizeof(int), stream);
  hipMemsetAsync(sum1, 0, 384 * sizeof(float), stream);

  // ---- build CSR (dst -> list of src)
  deg_kernel<<<(E + 255) / 256, 256, 0, stream>>>(dst, deg, E);
  scan_kernel<<<1, 1024, 0, stream>>>(deg, row_start, N);
  hipMemcpyAsync(cursor, row_start, (size_t)N * sizeof(int),
                 hipMemcpyDeviceToDevice, stream);
  fill_kernel<<<(E + 255) / 256, 256, 0, stream>>>(src, dst, cursor, eidx, E);

  // ---- layer 1: gather-mean x, SAGE conv, ReLU -> h1
  gather_mean_kernel<100><<<(N + 3) / 4, 256, 0, stream>>>(x, eidx, row_start, deg, bufA, N);
  sage_kernel<100><<<(N + 15) / 16, 128, 0, stream>>>(bufA, x, Wl1, bl1, Wr1, h1, N);

  // ---- layer 2: gather-mean h1, SAGE conv, ReLU -> h2
  gather_mean_kernel<128><<<(N + 3) / 4, 256, 0, stream>>>(h1, eidx, row_start, deg, bufA, N);
  sage_kernel<128><<<(N + 15) / 16, 128, 0, stream>>>(bufA, h1, Wl2, bl2, Wr2, h2, N);

  // ---- MLP layer 1: y1 = h2 @ W1 + b1 ; BN ; ReLU  (in bufA)
  gemm_kernel<128, 128><<<(N + 15) / 16, 128, 0, stream>>>(h2, W1, b1, bufA, N);
  colstats_kernel<<<240, 256, 0, stream>>>(bufA, N, 128, sum1, sq1);
  bn_relu_kernel<<<((size_t)N * 128 + 255) / 256, 256, 0, stream>>>(bufA, N, 128, sum1, sq1, g1, be1);

  // ---- MLP layer 2: y2 = z1 @ W2 + b2 ; BN ; ReLU  (in bufB)
  gemm_kernel<128, 64><<<(N + 15) / 16, 64, 0, stream>>>(bufA, W2, b2, bufB, N);
  colstats_kernel<<<240, 256, 0, stream>>>(bufB, N, 64, sum2, sq2);
  bn_relu_kernel<<<((size_t)N * 64 + 255) / 256, 256, 0, stream>>>(bufB, N, 64, sum2, sq2, g2, be2);

  // ---- head: out = z2 @ W3 + b3
  final_kernel<<<(N + 3) / 4, 256, 0, stream>>>(bufB, W3, b3, out0, N);
}

// Round 3
// 620.776 us; speedup vs baseline: 4.9270x; 1.2860x over previous
//
#include <hip/hip_runtime.h>

#define BN_EPS 1e-5f

typedef short s8v __attribute__((ext_vector_type(8)));
typedef float f4v __attribute__((ext_vector_type(4)));

__device__ __forceinline__ unsigned short f2bf(float f) {
  union { float f; unsigned u; } v; v.f = f;
  unsigned r = v.u + 0x7FFF + ((v.u >> 16) & 1);
  return (unsigned short)(r >> 16);
}
__device__ __forceinline__ float bf2f(unsigned short u) {
  union { unsigned u; float f; } v; v.u = ((unsigned)u) << 16; return v.f;
}

// ---------------------------------------------------------------- degree histogram (int)
__global__ __launch_bounds__(256) void deg_kernel(const int* __restrict__ dst,
                                                  int* __restrict__ deg, int E) {
  int e = blockIdx.x * 256 + threadIdx.x;
  if (e < E) atomicAdd(&deg[dst[e]], 1);
}

// ---------------------------------------------------------------- exclusive scan (1 block)
__global__ __launch_bounds__(1024) void scan_kernel(const int* __restrict__ deg,
                                                    int* __restrict__ row_start, int N) {
  __shared__ int partial[1024];
  int tid = threadIdx.x;
  int chunk = (N + 1023) / 1024;
  int base = tid * chunk;
  int s = 0;
  for (int i = 0; i < chunk; ++i) {
    int idx = base + i;
    if (idx < N) s += deg[idx];
  }
  partial[tid] = s;
  __syncthreads();
  for (int d = 1; d < 1024; d <<= 1) {
    int t = (tid >= d) ? partial[tid - d] : 0;
    __syncthreads();
    partial[tid] += t;
    __syncthreads();
  }
  int off = (tid == 0) ? 0 : partial[tid - 1];
  for (int i = 0; i < chunk; ++i) {
    int idx = base + i;
    if (idx < N) { row_start[idx] = off; off += deg[idx]; }
  }
}

// ---------------------------------------------------------------- CSR fill
__global__ __launch_bounds__(256) void fill_kernel(const int* __restrict__ src,
    const int* __restrict__ dst, int* __restrict__ cursor,
    int* __restrict__ eidx, int E) {
  int e = blockIdx.x * 256 + threadIdx.x;
  if (e >= E) return;
  int p = atomicAdd(&cursor[dst[e]], 1);
  eidx[p] = src[e];
}

// ------------------------------------------- x (fp32, F=100) -> xb (bf16, padded to 128)
__global__ __launch_bounds__(256) void xcast_kernel(const float* __restrict__ x,
    unsigned short* __restrict__ xb, int N) {
  int t = blockIdx.x * 256 + threadIdx.x;
  if (t >= N * 128) return;
  int col = t & 127;
  int n = t >> 7;
  xb[t] = (col < 100) ? f2bf(x[n * 100 + col]) : (unsigned short)0;
}

// ------------------------------- W (fp32 [K][C]) -> Wt (bf16 [C][128], k-padded w/ zeros)
__global__ __launch_bounds__(256) void wprep_kernel(const float* __restrict__ W,
    unsigned short* __restrict__ Wt, int K, int C) {
  int t = blockIdx.x * 256 + threadIdx.x;
  if (t >= C * 128) return;
  int c = t >> 7;
  int k = t & 127;
  Wt[t] = (k < K) ? f2bf(W[k * C + c]) : (unsigned short)0;
}

// ------------------------------------------ gather mean over bf16 rows (1 wave / node)
// feat: bf16 [N][128]; each lane handles 2 cols via one dword load per neighbor row.
__global__ __launch_bounds__(256) void gather_kernel(
    const unsigned short* __restrict__ feat, const int* __restrict__ eidx,
    const int* __restrict__ row_start, const int* __restrict__ deg,
    unsigned short* __restrict__ mean_out, int N) {
  int wave = threadIdx.x >> 6;
  int lane = threadIdx.x & 63;
  int node = blockIdx.x * 4 + wave;
  if (node >= N) return;
  int beg = row_start[node];
  int d = deg[node];
  float a0 = 0.0f, a1 = 0.0f;
  int i = 0;
  for (; i + 1 < d; i += 2) {
    int s0 = eidx[beg + i];
    int s1 = eidx[beg + i + 1];
    unsigned v0 = ((const unsigned*)(feat + (size_t)s0 * 128))[lane];
    unsigned v1 = ((const unsigned*)(feat + (size_t)s1 * 128))[lane];
    a0 += bf2f((unsigned short)v0) + bf2f((unsigned short)v1);
    a1 += bf2f((unsigned short)(v0 >> 16)) + bf2f((unsigned short)(v1 >> 16));
  }
  if (i < d) {
    unsigned v0 = ((const unsigned*)(feat + (size_t)eidx[beg + i] * 128))[lane];
    a0 += bf2f((unsigned short)v0);
    a1 += bf2f((unsigned short)(v0 >> 16));
  }
  float inv = 1.0f / fmaxf((float)d, 1.0f);
  unsigned o = (unsigned)f2bf(a0 * inv) | ((unsigned)f2bf(a1 * inv) << 16);
  ((unsigned*)(mean_out + (size_t)node * 128))[lane] = o;
}

// --------------------------------------------------------- MFMA GEMM (K padded to 128)
// out[n][c] = sum_k A1[n][k]*W1t[c][k] (+ A2[n][k]*W2t[c][k]) + bias[c]  (opt. ReLU)
// Block: 256 thr = 4 waves, wave handles 16 rows x COLS. D staged via LDS for coalesced
// stores. A/B frags loaded straight from global bf16 (A rows / Wt rows contiguous in k).
template<int COLS, bool DUAL, bool RELU, bool BF16OUT>
__global__ __launch_bounds__(256) void mfma_gemm_kernel(
    const unsigned short* __restrict__ A1, const unsigned short* __restrict__ W1t,
    const unsigned short* __restrict__ A2, const unsigned short* __restrict__ W2t,
    const float* __restrict__ bias,
    float* __restrict__ outF, unsigned short* __restrict__ outB, int N) {
  const int CT = COLS / 16;
  __shared__ float lds[64][COLS + 4];   // stride COLS+4 -> 2-way LDS aliasing (free)
  int wave = threadIdx.x >> 6;
  int lane = threadIdx.x & 63;
  int quad = lane >> 4;
  int m = lane & 15;
  int n0 = blockIdx.x * 64 + wave * 16;
  bool valid = (n0 < N);   // N multiple of 16 -> tiles fully in or out

  f4v acc[CT];
#pragma unroll
  for (int ct = 0; ct < CT; ++ct) acc[ct] = (f4v){0.f, 0.f, 0.f, 0.f};

  if (valid) {
    const unsigned short* a1p = A1 + (size_t)(n0 + m) * 128 + quad * 8;
    const unsigned short* a2p = DUAL ? (A2 + (size_t)(n0 + m) * 128 + quad * 8) : nullptr;
#pragma unroll
    for (int k0 = 0; k0 < 128; k0 += 32) {
      s8v a1 = *(const s8v*)(a1p + k0);
      s8v a2;
      if (DUAL) a2 = *(const s8v*)(a2p + k0);
#pragma unroll
      for (int ct = 0; ct < CT; ++ct) {
        s8v b1 = *(const s8v*)(W1t + (size_t)(ct * 16 + m) * 128 + k0 + quad * 8);
        acc[ct] = __builtin_amdgcn_mfma_f32_16x16x32_bf16(a1, b1, acc[ct], 0, 0, 0);
        if (DUAL) {
          s8v b2 = *(const s8v*)(W2t + (size_t)(ct * 16 + m) * 128 + k0 + quad * 8);
          acc[ct] = __builtin_amdgcn_mfma_f32_16x16x32_bf16(a2, b2, acc[ct], 0, 0, 0);
        }
      }
    }
    // epilogue: bias (+relu) into LDS; D layout col=lane&15, row=quad*4+reg
#pragma unroll
    for (int ct = 0; ct < CT; ++ct) {
      int col = ct * 16 + m;
      float b = bias[col];
#pragma unroll
      for (int r = 0; r < 4; ++r) {
        float v = acc[ct][r] + b;
        if (RELU) v = fmaxf(v, 0.0f);
        lds[wave * 16 + quad * 4 + r][col] = v;
      }
    }
  }
  __syncthreads();
  // coalesced cooperative store
  int blk = blockIdx.x * 64;
  for (int idx = threadIdx.x; idx < 64 * COLS; idx += 256) {
    int row = idx / COLS;
    int col = idx % COLS;
    int gr = blk + row;
    if (gr < N) {
      float v = lds[row][col];
      outF[(size_t)gr * COLS + col] = v;
      if (BF16OUT) outB[(size_t)gr * COLS + col] = f2bf(v);
    }
  }
}

// ------------------------------------------------------- per-column sum / sumsq
__global__ __launch_bounds__(256) void colstats_kernel(const float* __restrict__ y,
    int N, int C, float* __restrict__ sum, float* __restrict__ sumsq) {
  int tid = blockIdx.x * 256 + threadIdx.x;
  int total = gridDim.x * 256;
  int col = tid % C;
  int row0 = tid / C;
  int stride = total / C;
  float s = 0.0f, ss = 0.0f;
  for (int r = row0; r < N; r += stride) {
    float v = y[(size_t)r * C + col];
    s += v;
    ss += v * v;
  }
  atomicAdd(&sum[col], s);
  atomicAdd(&sumsq[col], ss);
}

// ------------------------------------------------- BN (train) + ReLU, in-place (+bf16)
template<bool BF16OUT>
__global__ __launch_bounds__(256) void bn_relu_kernel(float* __restrict__ y,
    int N, int C, const float* __restrict__ sum, const float* __restrict__ sumsq,
    const float* __restrict__ g, const float* __restrict__ be,
    unsigned short* __restrict__ yb) {
  int t = blockIdx.x * 256 + threadIdx.x;
  if (t >= N * C) return;
  int col = t % C;
  float invN = 1.0f / (float)N;
  float m = sum[col] * invN;
  float v = sumsq[col] * invN - m * m;
  float val = (y[t] - m) * rsqrtf(v + BN_EPS) * g[col] + be[col];
  val = fmaxf(val, 0.0f);
  y[t] = val;
  if (BF16OUT) yb[t] = f2bf(val);
}

// ------------------------------------------------------------- final head: z @ W3 + b3
__global__ __launch_bounds__(256) void final_kernel(const float* __restrict__ z,
    const float* __restrict__ W3, const float* __restrict__ b3,
    float* __restrict__ out, int N) {
  int wave = threadIdx.x >> 6;
  int lane = threadIdx.x & 63;
  int i = blockIdx.x * 4 + wave;
  if (i >= N) return;
  float v = z[(size_t)i * 64 + lane] * W3[lane];
#pragma unroll
  for (int off = 32; off > 0; off >>= 1) v += __shfl_down(v, off);
  if (lane == 0) out[i] = v + b3[0];
}

// ================================================================ launch
extern "C" void kernel_launch(void* const* d_in, const int* in_sizes, int n_in,
                              void* d_out, int out_size, void* d_ws, size_t ws_size,
                              hipStream_t stream) {
  const int F = 100, H = 128;
  const int N = in_sizes[0] / F;
  const int E = in_sizes[1] / 2;

  const float* x   = (const float*)d_in[0];
  const int* edge  = (const int*)d_in[1];
  const int* src   = edge;
  const int* dst   = edge + E;
  const float* Wl1 = (const float*)d_in[2];
  const float* bl1 = (const float*)d_in[3];
  const float* Wr1 = (const float*)d_in[4];
  const float* Wl2 = (const float*)d_in[5];
  const float* bl2 = (const float*)d_in[6];
  const float* Wr2 = (const float*)d_in[7];
  const float* W1  = (const float*)d_in[8];
  const float* b1  = (const float*)d_in[9];
  const float* g1  = (const float*)d_in[10];
  const float* be1 = (const float*)d_in[11];
  const float* W2  = (const float*)d_in[12];
  const float* b2  = (const float*)d_in[13];
  const float* g2  = (const float*)d_in[14];
  const float* be2 = (const float*)d_in[15];
  const float* W3  = (const float*)d_in[16];
  const float* b3  = (const float*)d_in[17];

  float* out0 = (float*)d_out;              // [N]
  float* h1   = out0 + N;                   // [N,128] fp32 (required output)
  float* h2   = h1 + (size_t)N * H;         // [N,128] fp32 (required output)

  // ---- workspace layout (all chunks 16B-aligned)
  char* wsp = (char*)d_ws;
  int* deg       = (int*)wsp;               wsp += (size_t)N * sizeof(int);
  int* row_start = (int*)wsp;               wsp += (size_t)N * sizeof(int);
  int* cursor    = (int*)wsp;               wsp += (size_t)N * sizeof(int);
  int* eidx      = (int*)wsp;               wsp += (size_t)E * sizeof(int);
  float* sum1    = (float*)wsp;             wsp += 128 * sizeof(float);
  float* sq1     = (float*)wsp;             wsp += 128 * sizeof(float);
  float* sum2    = (float*)wsp;             wsp += 64 * sizeof(float);
  float* sq2     = (float*)wsp;             wsp += 64 * sizeof(float);
  float* bufA    = (float*)wsp;             wsp += (size_t)N * 128 * sizeof(float); // y1/z1 fp32
  unsigned short* bfX = (unsigned short*)wsp; wsp += (size_t)N * 128 * 2; // xb, then mean2b
  unsigned short* bfM = (unsigned short*)wsp; wsp += (size_t)N * 128 * 2; // mean1b, then h2b
  unsigned short* bfH = (unsigned short*)wsp; wsp += (size_t)N * 128 * 2; // h1b, then z1b
  unsigned short* Wl1t = (unsigned short*)wsp; wsp += 128 * 128 * 2;
  unsigned short* Wr1t = (unsigned short*)wsp; wsp += 128 * 128 * 2;
  unsigned short* Wl2t = (unsigned short*)wsp; wsp += 128 * 128 * 2;
  unsigned short* Wr2t = (unsigned short*)wsp; wsp += 128 * 128 * 2;
  unsigned short* W1t  = (unsigned short*)wsp; wsp += 128 * 128 * 2;
  unsigned short* W2t  = (unsigned short*)wsp; wsp += 64 * 128 * 2;
  float* bufB = bufA;                       // z2 fp32 [N,64] aliases bufA (y1 dead by then)

  // ---- zero-init accumulated scratch (ws poisoned 0xAA each call)
  hipMemsetAsync(deg, 0, (size_t)N * sizeof(int), stream);
  hipMemsetAsync(sum1, 0, 384 * sizeof(float), stream);

  // ---- build CSR (dst -> list of src)
  deg_kernel<<<(E + 255) / 256, 256, 0, stream>>>(dst, deg, E);
  scan_kernel<<<1, 1024, 0, stream>>>(deg, row_start, N);
  hipMemcpyAsync(cursor, row_start, (size_t)N * sizeof(int),
                 hipMemcpyDeviceToDevice, stream);
  fill_kernel<<<(E + 255) / 256, 256, 0, stream>>>(src, dst, cursor, eidx, E);

  // ---- bf16 prep: x and all weight transposes
  xcast_kernel<<<((size_t)N * 128 + 255) / 256, 256, 0, stream>>>(x, bfX, N);
  wprep_kernel<<<64, 256, 0, stream>>>(Wl1, Wl1t, 100, 128);
  wprep_kernel<<<64, 256, 0, stream>>>(Wr1, Wr1t, 100, 128);
  wprep_kernel<<<64, 256, 0, stream>>>(Wl2, Wl2t, 128, 128);
  wprep_kernel<<<64, 256, 0, stream>>>(Wr2, Wr2t, 128, 128);
  wprep_kernel<<<64, 256, 0, stream>>>(W1, W1t, 128, 128);
  wprep_kernel<<<32, 256, 0, stream>>>(W2, W2t, 128, 64);

  int gemm_grid = (N + 63) / 64;

  // ---- layer 1: gather-mean(xb) -> bfM; sage MFMA -> h1 (fp32) + h1b (bf16, bfH)
  gather_kernel<<<(N + 3) / 4, 256, 0, stream>>>(bfX, eidx, row_start, deg, bfM, N);
  mfma_gemm_kernel<128, true, true, true><<<gemm_grid, 256, 0, stream>>>(
      bfM, Wl1t, bfX, Wr1t, bl1, h1, bfH, N);

  // ---- layer 2: gather-mean(h1b) -> bfX (xb dead); sage MFMA -> h2 + h2b (bfM)
  gather_kernel<<<(N + 3) / 4, 256, 0, stream>>>(bfH, eidx, row_start, deg, bfX, N);
  mfma_gemm_kernel<128, true, true, true><<<gemm_grid, 256, 0, stream>>>(
      bfX, Wl2t, bfH, Wr2t, bl2, h2, bfM, N);

  // ---- MLP layer 1: y1 = h2b @ W1 + b1 (bufA); BN+ReLU -> bufA + z1b (bfH)
  mfma_gemm_kernel<128, false, false, false><<<gemm_grid, 256, 0, stream>>>(
      bfM, W1t, nullptr, nullptr, b1, bufA, nullptr, N);
  colstats_kernel<<<240, 256, 0, stream>>>(bufA, N, 128, sum1, sq1);
  bn_relu_kernel<true><<<((size_t)N * 128 + 255) / 256, 256, 0, stream>>>(
      bufA, N, 128, sum1, sq1, g1, be1, bfH);

  // ---- MLP layer 2: y2 = z1b @ W2 + b2 (bufB = bufA alias); BN+ReLU
  mfma_gemm_kernel<64, false, false, false><<<gemm_grid, 256, 0, stream>>>(
      bfH, W2t, nullptr, nullptr, b2, bufB, nullptr, N);
  colstats_kernel<<<240, 256, 0, stream>>>(bufB, N, 64, sum2, sq2);
  bn_relu_kernel<false><<<((size_t)N * 64 + 255) / 256, 256, 0, stream>>>(
      bufB, N, 64, sum2, sq2, g2, be2, nullptr);

  // ---- head: out = z2 @ W3 + b3
  final_kernel<<<(N + 3) / 4, 256, 0, stream>>>(bufB, W3, b3, out0, N);
}

// Round 4
// 510.822 us; speedup vs baseline: 5.9875x; 1.2152x over previous
//
#include <hip/hip_runtime.h>

#define BN_EPS 1e-5f

typedef short s8v __attribute__((ext_vector_type(8)));
typedef float f4v __attribute__((ext_vector_type(4)));

__device__ __forceinline__ unsigned short f2bf(float f) {
  union { float f; unsigned u; } v; v.f = f;
  unsigned r = v.u + 0x7FFF + ((v.u >> 16) & 1);
  return (unsigned short)(r >> 16);
}
__device__ __forceinline__ float bf2f(unsigned short u) {
  union { unsigned u; float f; } v; v.u = ((unsigned)u) << 16; return v.f;
}

// ---------------------------------------------------------------- degree histogram (int)
__global__ __launch_bounds__(256) void deg_kernel(const int* __restrict__ dst,
                                                  int* __restrict__ deg, int E) {
  int e = blockIdx.x * 256 + threadIdx.x;
  if (e < E) atomicAdd(&deg[dst[e]], 1);
}

// ------------------------------------------- scan pass 1: per-block (1024 elems) totals
__global__ __launch_bounds__(256) void scan_partial_kernel(const int* __restrict__ deg,
    int* __restrict__ partials, int N) {
  __shared__ int sh[256];
  int t = threadIdx.x;
  int base = blockIdx.x * 1024 + t * 4;
  int s = 0;
#pragma unroll
  for (int i = 0; i < 4; ++i) {
    int idx = base + i;
    if (idx < N) s += deg[idx];
  }
  sh[t] = s;
  __syncthreads();
  for (int d = 128; d > 0; d >>= 1) {
    if (t < d) sh[t] += sh[t + d];
    __syncthreads();
  }
  if (t == 0) partials[blockIdx.x] = sh[0];
}

// ------------------------------------------- scan pass 2: exclusive scan of partials
__global__ __launch_bounds__(256) void scan_offsets_kernel(const int* __restrict__ partials,
    int* __restrict__ blk_off, int G) {
  __shared__ int sh[256];
  int t = threadIdx.x;
  sh[t] = (t < G) ? partials[t] : 0;
  __syncthreads();
  for (int d = 1; d < 256; d <<= 1) {
    int v = (t >= d) ? sh[t - d] : 0;
    __syncthreads();
    sh[t] += v;
    __syncthreads();
  }
  if (t < G) blk_off[t] = (t == 0) ? 0 : sh[t - 1];
}

// ------------------- scan pass 3: block-local exclusive scan + offset -> row_start, cursor
__global__ __launch_bounds__(256) void scan_scatter_kernel(const int* __restrict__ deg,
    const int* __restrict__ blk_off, int* __restrict__ row_start,
    int* __restrict__ cursor, int N) {
  __shared__ int sh[256];
  int t = threadIdx.x;
  int base = blockIdx.x * 1024 + t * 4;
  int v[4];
#pragma unroll
  for (int i = 0; i < 4; ++i) v[i] = (base + i < N) ? deg[base + i] : 0;
  int tot = v[0] + v[1] + v[2] + v[3];
  sh[t] = tot;
  __syncthreads();
  for (int d = 1; d < 256; d <<= 1) {
    int u = (t >= d) ? sh[t - d] : 0;
    __syncthreads();
    sh[t] += u;
    __syncthreads();
  }
  int off = blk_off[blockIdx.x] + ((t == 0) ? 0 : sh[t - 1]);
#pragma unroll
  for (int i = 0; i < 4; ++i) {
    int idx = base + i;
    if (idx < N) { row_start[idx] = off; cursor[idx] = off; off += v[i]; }
  }
}

// ---------------------------------------------------------------- CSR fill
__global__ __launch_bounds__(256) void fill_kernel(const int* __restrict__ src,
    const int* __restrict__ dst, int* __restrict__ cursor,
    int* __restrict__ eidx, int E) {
  int e = blockIdx.x * 256 + threadIdx.x;
  if (e >= E) return;
  int p = atomicAdd(&cursor[dst[e]], 1);
  eidx[p] = src[e];
}

// ------------------------------------------- x (fp32, F=100) -> xb (bf16, padded to 128)
__global__ __launch_bounds__(256) void xcast_kernel(const float* __restrict__ x,
    unsigned short* __restrict__ xb, int N) {
  int t = blockIdx.x * 256 + threadIdx.x;
  if (t >= N * 128) return;
  int col = t & 127;
  int n = t >> 7;
  xb[t] = (col < 100) ? f2bf(x[n * 100 + col]) : (unsigned short)0;
}

// ------------------------------- W (fp32 [K][C]) -> Wt (bf16 [C][128], k-padded w/ zeros)
__global__ __launch_bounds__(256) void wprep_kernel(const float* __restrict__ W,
    unsigned short* __restrict__ Wt, int K, int C) {
  int t = blockIdx.x * 256 + threadIdx.x;
  if (t >= C * 128) return;
  int c = t >> 7;
  int k = t & 127;
  Wt[t] = (k < K) ? f2bf(W[k * C + c]) : (unsigned short)0;
}

// ------------------------------------------ gather mean over bf16 rows (1 wave / node)
// Indices pre-loaded coalesced into lanes, broadcast via shfl -> row loads have no
// memory dependency and pipeline 4-deep.
__global__ __launch_bounds__(256) void gather_kernel(
    const unsigned short* __restrict__ feat, const int* __restrict__ eidx,
    const int* __restrict__ row_start, const int* __restrict__ deg,
    unsigned short* __restrict__ mean_out, int N) {
  int wave = threadIdx.x >> 6;
  int lane = threadIdx.x & 63;
  int node = blockIdx.x * 4 + wave;
  if (node >= N) return;
  int beg = row_start[node];
  int d = deg[node];
  float a0 = 0.0f, a1 = 0.0f;
  for (int i0 = 0; i0 < d; i0 += 64) {
    int cnt = min(64, d - i0);
    int my = (lane < cnt) ? eidx[beg + i0 + lane] : 0;
    int j = 0;
    for (; j + 3 < cnt; j += 4) {
      int s0 = __shfl(my, j + 0);
      int s1 = __shfl(my, j + 1);
      int s2 = __shfl(my, j + 2);
      int s3 = __shfl(my, j + 3);
      unsigned v0 = ((const unsigned*)(feat + (size_t)s0 * 128))[lane];
      unsigned v1 = ((const unsigned*)(feat + (size_t)s1 * 128))[lane];
      unsigned v2 = ((const unsigned*)(feat + (size_t)s2 * 128))[lane];
      unsigned v3 = ((const unsigned*)(feat + (size_t)s3 * 128))[lane];
      a0 += bf2f((unsigned short)v0) + bf2f((unsigned short)v1)
          + bf2f((unsigned short)v2) + bf2f((unsigned short)v3);
      a1 += bf2f((unsigned short)(v0 >> 16)) + bf2f((unsigned short)(v1 >> 16))
          + bf2f((unsigned short)(v2 >> 16)) + bf2f((unsigned short)(v3 >> 16));
    }
    for (; j < cnt; ++j) {
      int s0 = __shfl(my, j);
      unsigned v0 = ((const unsigned*)(feat + (size_t)s0 * 128))[lane];
      a0 += bf2f((unsigned short)v0);
      a1 += bf2f((unsigned short)(v0 >> 16));
    }
  }
  float inv = 1.0f / fmaxf((float)d, 1.0f);
  unsigned o = (unsigned)f2bf(a0 * inv) | ((unsigned)f2bf(a1 * inv) << 16);
  ((unsigned*)(mean_out + (size_t)node * 128))[lane] = o;
}

// --------------------------------------------------------- MFMA GEMM (K padded to 128)
template<int COLS, bool DUAL, bool RELU, bool BF16OUT>
__global__ __launch_bounds__(256) void mfma_gemm_kernel(
    const unsigned short* __restrict__ A1, const unsigned short* __restrict__ W1t,
    const unsigned short* __restrict__ A2, const unsigned short* __restrict__ W2t,
    const float* __restrict__ bias,
    float* __restrict__ outF, unsigned short* __restrict__ outB, int N) {
  const int CT = COLS / 16;
  __shared__ float lds[64][COLS + 4];
  int wave = threadIdx.x >> 6;
  int lane = threadIdx.x & 63;
  int quad = lane >> 4;
  int m = lane & 15;
  int n0 = blockIdx.x * 64 + wave * 16;
  bool valid = (n0 < N);

  f4v acc[CT];
#pragma unroll
  for (int ct = 0; ct < CT; ++ct) acc[ct] = (f4v){0.f, 0.f, 0.f, 0.f};

  if (valid) {
    const unsigned short* a1p = A1 + (size_t)(n0 + m) * 128 + quad * 8;
    const unsigned short* a2p = DUAL ? (A2 + (size_t)(n0 + m) * 128 + quad * 8) : nullptr;
#pragma unroll
    for (int k0 = 0; k0 < 128; k0 += 32) {
      s8v a1 = *(const s8v*)(a1p + k0);
      s8v a2;
      if (DUAL) a2 = *(const s8v*)(a2p + k0);
#pragma unroll
      for (int ct = 0; ct < CT; ++ct) {
        s8v b1 = *(const s8v*)(W1t + (size_t)(ct * 16 + m) * 128 + k0 + quad * 8);
        acc[ct] = __builtin_amdgcn_mfma_f32_16x16x32_bf16(a1, b1, acc[ct], 0, 0, 0);
        if (DUAL) {
          s8v b2 = *(const s8v*)(W2t + (size_t)(ct * 16 + m) * 128 + k0 + quad * 8);
          acc[ct] = __builtin_amdgcn_mfma_f32_16x16x32_bf16(a2, b2, acc[ct], 0, 0, 0);
        }
      }
    }
#pragma unroll
    for (int ct = 0; ct < CT; ++ct) {
      int col = ct * 16 + m;
      float b = bias[col];
#pragma unroll
      for (int r = 0; r < 4; ++r) {
        float v = acc[ct][r] + b;
        if (RELU) v = fmaxf(v, 0.0f);
        lds[wave * 16 + quad * 4 + r][col] = v;
      }
    }
  }
  __syncthreads();
  int blk = blockIdx.x * 64;
  for (int idx = threadIdx.x; idx < 64 * COLS; idx += 256) {
    int row = idx / COLS;
    int col = idx % COLS;
    int gr = blk + row;
    if (gr < N) {
      float v = lds[row][col];
      outF[(size_t)gr * COLS + col] = v;
      if (BF16OUT) outB[(size_t)gr * COLS + col] = f2bf(v);
    }
  }
}

// ------------------------------------------------------- per-column sum / sumsq
__global__ __launch_bounds__(256) void colstats_kernel(const float* __restrict__ y,
    int N, int C, float* __restrict__ sum, float* __restrict__ sumsq) {
  int tid = blockIdx.x * 256 + threadIdx.x;
  int total = gridDim.x * 256;
  int col = tid % C;
  int row0 = tid / C;
  int stride = total / C;
  float s = 0.0f, ss = 0.0f;
  for (int r = row0; r < N; r += stride) {
    float v = y[(size_t)r * C + col];
    s += v;
    ss += v * v;
  }
  atomicAdd(&sum[col], s);
  atomicAdd(&sumsq[col], ss);
}

// ------------------------------------------------- BN (train) + ReLU, in-place (+bf16)
template<bool BF16OUT>
__global__ __launch_bounds__(256) void bn_relu_kernel(float* __restrict__ y,
    int N, int C, const float* __restrict__ sum, const float* __restrict__ sumsq,
    const float* __restrict__ g, const float* __restrict__ be,
    unsigned short* __restrict__ yb) {
  int t = blockIdx.x * 256 + threadIdx.x;
  if (t >= N * C) return;
  int col = t % C;
  float invN = 1.0f / (float)N;
  float m = sum[col] * invN;
  float v = sumsq[col] * invN - m * m;
  float val = (y[t] - m) * rsqrtf(v + BN_EPS) * g[col] + be[col];
  val = fmaxf(val, 0.0f);
  y[t] = val;
  if (BF16OUT) yb[t] = f2bf(val);
}

// ------------------------------------------------------------- final head: z @ W3 + b3
__global__ __launch_bounds__(256) void final_kernel(const float* __restrict__ z,
    const float* __restrict__ W3, const float* __restrict__ b3,
    float* __restrict__ out, int N) {
  int wave = threadIdx.x >> 6;
  int lane = threadIdx.x & 63;
  int i = blockIdx.x * 4 + wave;
  if (i >= N) return;
  float v = z[(size_t)i * 64 + lane] * W3[lane];
#pragma unroll
  for (int off = 32; off > 0; off >>= 1) v += __shfl_down(v, off);
  if (lane == 0) out[i] = v + b3[0];
}

// ================================================================ launch
extern "C" void kernel_launch(void* const* d_in, const int* in_sizes, int n_in,
                              void* d_out, int out_size, void* d_ws, size_t ws_size,
                              hipStream_t stream) {
  const int F = 100, H = 128;
  const int N = in_sizes[0] / F;
  const int E = in_sizes[1] / 2;

  const float* x   = (const float*)d_in[0];
  const int* edge  = (const int*)d_in[1];
  const int* src   = edge;
  const int* dst   = edge + E;
  const float* Wl1 = (const float*)d_in[2];
  const float* bl1 = (const float*)d_in[3];
  const float* Wr1 = (const float*)d_in[4];
  const float* Wl2 = (const float*)d_in[5];
  const float* bl2 = (const float*)d_in[6];
  const float* Wr2 = (const float*)d_in[7];
  const float* W1  = (const float*)d_in[8];
  const float* b1  = (const float*)d_in[9];
  const float* g1  = (const float*)d_in[10];
  const float* be1 = (const float*)d_in[11];
  const float* W2  = (const float*)d_in[12];
  const float* b2  = (const float*)d_in[13];
  const float* g2  = (const float*)d_in[14];
  const float* be2 = (const float*)d_in[15];
  const float* W3  = (const float*)d_in[16];
  const float* b3  = (const float*)d_in[17];

  float* out0 = (float*)d_out;              // [N]
  float* h1   = out0 + N;                   // [N,128] fp32 (required output)
  float* h2   = h1 + (size_t)N * H;         // [N,128] fp32 (required output)

  const int SCAN_G = (N + 1023) / 1024;     // 49 for N=50000 (must be <= 256)

  // ---- workspace layout (all chunks 16B-aligned)
  char* wsp = (char*)d_ws;
  int* deg       = (int*)wsp;               wsp += (size_t)N * sizeof(int);
  int* row_start = (int*)wsp;               wsp += (size_t)N * sizeof(int);
  int* cursor    = (int*)wsp;               wsp += (size_t)N * sizeof(int);
  int* eidx      = (int*)wsp;               wsp += (size_t)E * sizeof(int);
  int* partials  = (int*)wsp;               wsp += 256 * sizeof(int);
  int* blk_off   = (int*)wsp;               wsp += 256 * sizeof(int);
  float* sum1    = (float*)wsp;             wsp += 128 * sizeof(float);
  float* sq1     = (float*)wsp;             wsp += 128 * sizeof(float);
  float* sum2    = (float*)wsp;             wsp += 64 * sizeof(float);
  float* sq2     = (float*)wsp;             wsp += 64 * sizeof(float);
  float* bufA    = (float*)wsp;             wsp += (size_t)N * 128 * sizeof(float);
  unsigned short* bfX = (unsigned short*)wsp; wsp += (size_t)N * 128 * 2;
  unsigned short* bfM = (unsigned short*)wsp; wsp += (size_t)N * 128 * 2;
  unsigned short* bfH = (unsigned short*)wsp; wsp += (size_t)N * 128 * 2;
  unsigned short* Wl1t = (unsigned short*)wsp; wsp += 128 * 128 * 2;
  unsigned short* Wr1t = (unsigned short*)wsp; wsp += 128 * 128 * 2;
  unsigned short* Wl2t = (unsigned short*)wsp; wsp += 128 * 128 * 2;
  unsigned short* Wr2t = (unsigned short*)wsp; wsp += 128 * 128 * 2;
  unsigned short* W1t  = (unsigned short*)wsp; wsp += 128 * 128 * 2;
  unsigned short* W2t  = (unsigned short*)wsp; wsp += 64 * 128 * 2;
  float* bufB = bufA;

  // ---- zero-init accumulated scratch
  hipMemsetAsync(deg, 0, (size_t)N * sizeof(int), stream);
  hipMemsetAsync(sum1, 0, 384 * sizeof(float), stream);

  // ---- build CSR (dst -> list of src)
  deg_kernel<<<(E + 255) / 256, 256, 0, stream>>>(dst, deg, E);
  scan_partial_kernel<<<SCAN_G, 256, 0, stream>>>(deg, partials, N);
  scan_offsets_kernel<<<1, 256, 0, stream>>>(partials, blk_off, SCAN_G);
  scan_scatter_kernel<<<SCAN_G, 256, 0, stream>>>(deg, blk_off, row_start, cursor, N);
  fill_kernel<<<(E + 255) / 256, 256, 0, stream>>>(src, dst, cursor, eidx, E);

  // ---- bf16 prep: x and all weight transposes
  xcast_kernel<<<((size_t)N * 128 + 255) / 256, 256, 0, stream>>>(x, bfX, N);
  wprep_kernel<<<64, 256, 0, stream>>>(Wl1, Wl1t, 100, 128);
  wprep_kernel<<<64, 256, 0, stream>>>(Wr1, Wr1t, 100, 128);
  wprep_kernel<<<64, 256, 0, stream>>>(Wl2, Wl2t, 128, 128);
  wprep_kernel<<<64, 256, 0, stream>>>(Wr2, Wr2t, 128, 128);
  wprep_kernel<<<64, 256, 0, stream>>>(W1, W1t, 128, 128);
  wprep_kernel<<<32, 256, 0, stream>>>(W2, W2t, 128, 64);

  int gemm_grid = (N + 63) / 64;

  // ---- layer 1
  gather_kernel<<<(N + 3) / 4, 256, 0, stream>>>(bfX, eidx, row_start, deg, bfM, N);
  mfma_gemm_kernel<128, true, true, true><<<gemm_grid, 256, 0, stream>>>(
      bfM, Wl1t, bfX, Wr1t, bl1, h1, bfH, N);

  // ---- layer 2
  gather_kernel<<<(N + 3) / 4, 256, 0, stream>>>(bfH, eidx, row_start, deg, bfX, N);
  mfma_gemm_kernel<128, true, true, true><<<gemm_grid, 256, 0, stream>>>(
      bfX, Wl2t, bfH, Wr2t, bl2, h2, bfM, N);

  // ---- MLP layer 1
  mfma_gemm_kernel<128, false, false, false><<<gemm_grid, 256, 0, stream>>>(
      bfM, W1t, nullptr, nullptr, b1, bufA, nullptr, N);
  colstats_kernel<<<240, 256, 0, stream>>>(bufA, N, 128, sum1, sq1);
  bn_relu_kernel<true><<<((size_t)N * 128 + 255) / 256, 256, 0, stream>>>(
      bufA, N, 128, sum1, sq1, g1, be1, bfH);

  // ---- MLP layer 2
  mfma_gemm_kernel<64, false, false, false><<<gemm_grid, 256, 0, stream>>>(
      bfH, W2t, nullptr, nullptr, b2, bufB, nullptr, N);
  colstats_kernel<<<240, 256, 0, stream>>>(bufB, N, 64, sum2, sq2);
  bn_relu_kernel<false><<<((size_t)N * 64 + 255) / 256, 256, 0, stream>>>(
      bufB, N, 64, sum2, sq2, g2, be2, nullptr);

  // ---- head
  final_kernel<<<(N + 3) / 4, 256, 0, stream>>>(bufB, W3, b3, out0, N);
}

// Round 5
// 494.783 us; speedup vs baseline: 6.1816x; 1.0324x over previous
//
#include <hip/hip_runtime.h>

#define BN_EPS 1e-5f

typedef short s8v __attribute__((ext_vector_type(8)));
typedef float f4v __attribute__((ext_vector_type(4)));

__device__ __forceinline__ unsigned short f2bf(float f) {
  union { float f; unsigned u; } v; v.f = f;
  unsigned r = v.u + 0x7FFF + ((v.u >> 16) & 1);
  return (unsigned short)(r >> 16);
}
__device__ __forceinline__ float bf2f(unsigned short u) {
  union { unsigned u; float f; } v; v.u = ((unsigned)u) << 16; return v.f;
}

// ---------------------------------------------------------------- degree histogram (int)
__global__ __launch_bounds__(256) void deg_kernel(const int* __restrict__ dst,
                                                  int* __restrict__ deg, int E) {
  int e = blockIdx.x * 256 + threadIdx.x;
  if (e < E) atomicAdd(&deg[dst[e]], 1);
}

// ------------------------------------------- scan pass 1: per-block (1024 elems) totals
__global__ __launch_bounds__(256) void scan_partial_kernel(const int* __restrict__ deg,
    int* __restrict__ partials, int N) {
  __shared__ int sh[256];
  int t = threadIdx.x;
  int base = blockIdx.x * 1024 + t * 4;
  int s = 0;
#pragma unroll
  for (int i = 0; i < 4; ++i) {
    int idx = base + i;
    if (idx < N) s += deg[idx];
  }
  sh[t] = s;
  __syncthreads();
  for (int d = 128; d > 0; d >>= 1) {
    if (t < d) sh[t] += sh[t + d];
    __syncthreads();
  }
  if (t == 0) partials[blockIdx.x] = sh[0];
}

// ------------------------------------------- scan pass 2: exclusive scan of partials
__global__ __launch_bounds__(256) void scan_offsets_kernel(const int* __restrict__ partials,
    int* __restrict__ blk_off, int G) {
  __shared__ int sh[256];
  int t = threadIdx.x;
  sh[t] = (t < G) ? partials[t] : 0;
  __syncthreads();
  for (int d = 1; d < 256; d <<= 1) {
    int v = (t >= d) ? sh[t - d] : 0;
    __syncthreads();
    sh[t] += v;
    __syncthreads();
  }
  if (t < G) blk_off[t] = (t == 0) ? 0 : sh[t - 1];
}

// ----- scan pass 3: block-local exclusive scan + offset -> row_start, bucket cursors
__global__ __launch_bounds__(256) void scan_scatter_kernel(const int* __restrict__ deg,
    const int* __restrict__ blk_off, int* __restrict__ row_start,
    int* __restrict__ gcursor, int N) {
  __shared__ int sh[256];
  int t = threadIdx.x;
  int base = blockIdx.x * 1024 + t * 4;
  int v[4];
#pragma unroll
  for (int i = 0; i < 4; ++i) v[i] = (base + i < N) ? deg[base + i] : 0;
  sh[t] = v[0] + v[1] + v[2] + v[3];
  __syncthreads();
  for (int d = 1; d < 256; d <<= 1) {
    int u = (t >= d) ? sh[t - d] : 0;
    __syncthreads();
    sh[t] += u;
    __syncthreads();
  }
  int off = blk_off[blockIdx.x] + ((t == 0) ? 0 : sh[t - 1]);
#pragma unroll
  for (int i = 0; i < 4; ++i) {
    int idx = base + i;
    if (idx < N) {
      row_start[idx] = off;
      if ((idx & 127) == 0) gcursor[idx >> 7] = off;  // pairs cursor = CSR bucket start
      off += v[i];
    }
  }
}

// ------------------- CSR phase A: LDS-staged bucket scatter (kills partial-line writes)
// pairs[] shares the CSR bucket layout: bucket b's region = [row_start[b*128), ...).
#define CHUNK 8192
#define NBMAX 512
__global__ __launch_bounds__(256) void csr_bucket_kernel(
    const int* __restrict__ src, const int* __restrict__ dst,
    int* __restrict__ gcursor, unsigned* __restrict__ pairs, int E) {
  __shared__ int h[NBMAX];
  __shared__ int off[NBMAX];
  __shared__ int cnt2[NBMAX];
  __shared__ int gadj[NBMAX];
  __shared__ unsigned pbuf[CHUNK];
  __shared__ unsigned short bidx[CHUNK];
  int t = threadIdx.x;
  int base = blockIdx.x * CHUNK;
  int cnt = min(CHUNK, E - base);
  for (int i = t; i < NBMAX; i += 256) { h[i] = 0; cnt2[i] = 0; }
  __syncthreads();
  // pass 1: bucket histogram
  for (int i = t; i < cnt; i += 256) atomicAdd(&h[dst[base + i] >> 7], 1);
  __syncthreads();
  // exclusive scan h -> off (Hillis-Steele, 512 wide, 2 elems/thread)
  off[t] = h[t]; off[t + 256] = h[t + 256];
  __syncthreads();
  for (int d = 1; d < 512; d <<= 1) {
    int v0 = (t >= d) ? off[t - d] : 0;
    int v1 = off[t + 256 - d];
    __syncthreads();
    off[t] += v0; off[t + 256] += v1;
    __syncthreads();
  }
  int e0 = off[t] - h[t];
  int e1 = off[t + 256] - h[t + 256];
  __syncthreads();
  off[t] = e0; off[t + 256] = e1;
  __syncthreads();
  // bulk-reserve global space per bucket
  for (int i = t; i < NBMAX; i += 256) {
    int c = h[i];
    if (c > 0) gadj[i] = atomicAdd(&gcursor[i], c) - off[i];
  }
  __syncthreads();
  // pass 2: place packed pairs into LDS, bucket-ordered
  for (int i = t; i < cnt; i += 256) {
    int s = src[base + i];
    int d = dst[base + i];
    int b = d >> 7;
    int p = off[b] + atomicAdd(&cnt2[b], 1);
    pbuf[p] = (unsigned)s | ((unsigned)d << 16);   // both < 2^16 (N=50000)
    bidx[p] = (unsigned short)b;
  }
  __syncthreads();
  // coalesced copy-out (contiguous runs per bucket)
  for (int i = t; i < cnt; i += 256)
    pairs[gadj[bidx[i]] + i] = pbuf[i];
}

// ------------------- CSR phase B: one block per bucket, private eidx region, LDS cursors
__global__ __launch_bounds__(256) void csr_fill_kernel(
    const unsigned* __restrict__ pairs, const int* __restrict__ row_start,
    int* __restrict__ eidx, int N, int E) {
  __shared__ int cur[128];
  int b = blockIdx.x;
  int node0 = b << 7;
  int t = threadIdx.x;
  if (t < 128) {
    int node = node0 + t;
    cur[t] = (node < N) ? row_start[node] : 0;
  }
  __syncthreads();
  int pbeg = row_start[node0];
  int pend = (node0 + 128 < N) ? row_start[node0 + 128] : E;
  for (int i = pbeg + t; i < pend; i += 256) {
    unsigned p = pairs[i];
    int pos = atomicAdd(&cur[(int)(p >> 16) - node0], 1);
    eidx[pos] = (int)(p & 0xFFFFu);
  }
}

// --------------- fused prep: xcast (blocks [0,xblocks)) + 6 weight transposes (352 blocks)
__global__ __launch_bounds__(256) void prep_kernel(
    const float* __restrict__ x, unsigned short* __restrict__ xb,
    const float* __restrict__ Wl1, const float* __restrict__ Wr1,
    const float* __restrict__ Wl2, const float* __restrict__ Wr2,
    const float* __restrict__ W1, const float* __restrict__ W2,
    unsigned short* __restrict__ Wl1t, unsigned short* __restrict__ Wr1t,
    unsigned short* __restrict__ Wl2t, unsigned short* __restrict__ Wr2t,
    unsigned short* __restrict__ W1t, unsigned short* __restrict__ W2t,
    int N, int xblocks) {
  int blk = blockIdx.x;
  if (blk < xblocks) {
    int t = blk * 256 + threadIdx.x;
    if (t < N * 128) {
      int col = t & 127;
      int n = t >> 7;
      xb[t] = (col < 100) ? f2bf(x[n * 100 + col]) : (unsigned short)0;
    }
    return;
  }
  int w = blk - xblocks;
  const float* W; unsigned short* Wt; int K, C, base;
  if (w < 64)       { W = Wl1; Wt = Wl1t; K = 100; C = 128; base = 0;   }
  else if (w < 128) { W = Wr1; Wt = Wr1t; K = 100; C = 128; base = 64;  }
  else if (w < 192) { W = Wl2; Wt = Wl2t; K = 128; C = 128; base = 128; }
  else if (w < 256) { W = Wr2; Wt = Wr2t; K = 128; C = 128; base = 192; }
  else if (w < 320) { W = W1;  Wt = W1t;  K = 128; C = 128; base = 256; }
  else              { W = W2;  Wt = W2t;  K = 128; C = 64;  base = 320; }
  int t = (w - base) * 256 + threadIdx.x;
  if (t >= C * 128) return;
  int c = t >> 7;
  int k = t & 127;
  Wt[t] = (k < K) ? f2bf(W[k * C + c]) : (unsigned short)0;
}

// ------------------------------------------ gather mean over bf16 rows (1 wave / node)
__global__ __launch_bounds__(256) void gather_kernel(
    const unsigned short* __restrict__ feat, const int* __restrict__ eidx,
    const int* __restrict__ row_start, const int* __restrict__ deg,
    unsigned short* __restrict__ mean_out, int N) {
  int wave = threadIdx.x >> 6;
  int lane = threadIdx.x & 63;
  int node = blockIdx.x * 4 + wave;
  if (node >= N) return;
  int beg = row_start[node];
  int d = deg[node];
  float a0 = 0.0f, a1 = 0.0f;
  for (int i0 = 0; i0 < d; i0 += 64) {
    int cnt = min(64, d - i0);
    int my = (lane < cnt) ? eidx[beg + i0 + lane] : 0;
    int j = 0;
    for (; j + 3 < cnt; j += 4) {
      int s0 = __shfl(my, j + 0);
      int s1 = __shfl(my, j + 1);
      int s2 = __shfl(my, j + 2);
      int s3 = __shfl(my, j + 3);
      unsigned v0 = ((const unsigned*)(feat + (size_t)s0 * 128))[lane];
      unsigned v1 = ((const unsigned*)(feat + (size_t)s1 * 128))[lane];
      unsigned v2 = ((const unsigned*)(feat + (size_t)s2 * 128))[lane];
      unsigned v3 = ((const unsigned*)(feat + (size_t)s3 * 128))[lane];
      a0 += bf2f((unsigned short)v0) + bf2f((unsigned short)v1)
          + bf2f((unsigned short)v2) + bf2f((unsigned short)v3);
      a1 += bf2f((unsigned short)(v0 >> 16)) + bf2f((unsigned short)(v1 >> 16))
          + bf2f((unsigned short)(v2 >> 16)) + bf2f((unsigned short)(v3 >> 16));
    }
    for (; j < cnt; ++j) {
      int s0 = __shfl(my, j);
      unsigned v0 = ((const unsigned*)(feat + (size_t)s0 * 128))[lane];
      a0 += bf2f((unsigned short)v0);
      a1 += bf2f((unsigned short)(v0 >> 16));
    }
  }
  float inv = 1.0f / fmaxf((float)d, 1.0f);
  unsigned o = (unsigned)f2bf(a0 * inv) | ((unsigned)f2bf(a1 * inv) << 16);
  ((unsigned*)(mean_out + (size_t)node * 128))[lane] = o;
}

// --------------------------------------------------------- MFMA GEMM (K padded to 128)
// Optional fused per-column sum/sumsq (BN stats) from the LDS-resident output tile.
template<int COLS, bool DUAL, bool RELU, bool BF16OUT, bool STATS>
__global__ __launch_bounds__(256) void mfma_gemm_kernel(
    const unsigned short* __restrict__ A1, const unsigned short* __restrict__ W1t,
    const unsigned short* __restrict__ A2, const unsigned short* __restrict__ W2t,
    const float* __restrict__ bias,
    float* __restrict__ outF, unsigned short* __restrict__ outB,
    float* __restrict__ sum, float* __restrict__ sq, int N) {
  const int CT = COLS / 16;
  __shared__ float lds[64][COLS + 4];
  int wave = threadIdx.x >> 6;
  int lane = threadIdx.x & 63;
  int quad = lane >> 4;
  int m = lane & 15;
  int n0 = blockIdx.x * 64 + wave * 16;
  bool valid = (n0 < N);

  f4v acc[CT];
#pragma unroll
  for (int ct = 0; ct < CT; ++ct) acc[ct] = (f4v){0.f, 0.f, 0.f, 0.f};

  if (valid) {
    const unsigned short* a1p = A1 + (size_t)(n0 + m) * 128 + quad * 8;
    const unsigned short* a2p = DUAL ? (A2 + (size_t)(n0 + m) * 128 + quad * 8) : nullptr;
#pragma unroll
    for (int k0 = 0; k0 < 128; k0 += 32) {
      s8v a1 = *(const s8v*)(a1p + k0);
      s8v a2;
      if (DUAL) a2 = *(const s8v*)(a2p + k0);
#pragma unroll
      for (int ct = 0; ct < CT; ++ct) {
        s8v b1 = *(const s8v*)(W1t + (size_t)(ct * 16 + m) * 128 + k0 + quad * 8);
        acc[ct] = __builtin_amdgcn_mfma_f32_16x16x32_bf16(a1, b1, acc[ct], 0, 0, 0);
        if (DUAL) {
          s8v b2 = *(const s8v*)(W2t + (size_t)(ct * 16 + m) * 128 + k0 + quad * 8);
          acc[ct] = __builtin_amdgcn_mfma_f32_16x16x32_bf16(a2, b2, acc[ct], 0, 0, 0);
        }
      }
    }
#pragma unroll
    for (int ct = 0; ct < CT; ++ct) {
      int col = ct * 16 + m;
      float b = bias[col];
#pragma unroll
      for (int r = 0; r < 4; ++r) {
        float v = acc[ct][r] + b;
        if (RELU) v = fmaxf(v, 0.0f);
        lds[wave * 16 + quad * 4 + r][col] = v;
      }
    }
  }
  __syncthreads();
  int blk = blockIdx.x * 64;
  float s = 0.0f, ss = 0.0f;
  for (int idx = threadIdx.x; idx < 64 * COLS; idx += 256) {
    int row = idx / COLS;
    int col = idx % COLS;   // constant per thread (256 % COLS == 0)
    int gr = blk + row;
    if (gr < N) {
      float v = lds[row][col];
      outF[(size_t)gr * COLS + col] = v;
      if (BF16OUT) outB[(size_t)gr * COLS + col] = f2bf(v);
      if (STATS) { s += v; ss += v * v; }
    }
  }
  if (STATS) {
    int col = threadIdx.x % COLS;
    atomicAdd(&sum[col], s);
    atomicAdd(&sq[col], ss);
  }
}

// ---------------------------------- BN (train) + ReLU: fp32 in -> bf16 out (C = 128)
__global__ __launch_bounds__(256) void bn_relu_kernel(const float* __restrict__ y,
    int N, const float* __restrict__ sum, const float* __restrict__ sumsq,
    const float* __restrict__ g, const float* __restrict__ be,
    unsigned short* __restrict__ yb) {
  int t = blockIdx.x * 256 + threadIdx.x;
  if (t >= N * 128) return;
  int col = t & 127;
  float invN = 1.0f / (float)N;
  float m = sum[col] * invN;
  float v = sumsq[col] * invN - m * m;
  float val = (y[t] - m) * rsqrtf(v + BN_EPS) * g[col] + be[col];
  yb[t] = f2bf(fmaxf(val, 0.0f));
}

// -------------------------- fused BN(train)+ReLU (64 cols) + head dot: out = z2@W3+b3
__global__ __launch_bounds__(256) void bn_head_kernel(const float* __restrict__ y2,
    const float* __restrict__ sum, const float* __restrict__ sumsq,
    const float* __restrict__ g, const float* __restrict__ be,
    const float* __restrict__ W3, const float* __restrict__ b3,
    float* __restrict__ out, int N) {
  int wave = threadIdx.x >> 6;
  int lane = threadIdx.x & 63;
  int row = blockIdx.x * 4 + wave;
  if (row >= N) return;
  float invN = 1.0f / (float)N;
  float m = sum[lane] * invN;
  float var = sumsq[lane] * invN - m * m;
  float val = (y2[(size_t)row * 64 + lane] - m) * rsqrtf(var + BN_EPS) * g[lane] + be[lane];
  val = fmaxf(val, 0.0f) * W3[lane];
#pragma unroll
  for (int off = 32; off > 0; off >>= 1) val += __shfl_down(val, off);
  if (lane == 0) out[row] = val + b3[0];
}

// ================================================================ launch
extern "C" void kernel_launch(void* const* d_in, const int* in_sizes, int n_in,
                              void* d_out, int out_size, void* d_ws, size_t ws_size,
                              hipStream_t stream) {
  const int F = 100, H = 128;
  const int N = in_sizes[0] / F;
  const int E = in_sizes[1] / 2;

  const float* x   = (const float*)d_in[0];
  const int* edge  = (const int*)d_in[1];
  const int* src   = edge;
  const int* dst   = edge + E;
  const float* Wl1 = (const float*)d_in[2];
  const float* bl1 = (const float*)d_in[3];
  const float* Wr1 = (const float*)d_in[4];
  const float* Wl2 = (const float*)d_in[5];
  const float* bl2 = (const float*)d_in[6];
  const float* Wr2 = (const float*)d_in[7];
  const float* W1  = (const float*)d_in[8];
  const float* b1  = (const float*)d_in[9];
  const float* g1  = (const float*)d_in[10];
  const float* be1 = (const float*)d_in[11];
  const float* W2  = (const float*)d_in[12];
  const float* b2  = (const float*)d_in[13];
  const float* g2  = (const float*)d_in[14];
  const float* be2 = (const float*)d_in[15];
  const float* W3  = (const float*)d_in[16];
  const float* b3  = (const float*)d_in[17];

  float* out0 = (float*)d_out;              // [N]
  float* h1   = out0 + N;                   // [N,128] fp32 (required output)
  float* h2   = h1 + (size_t)N * H;         // [N,128] fp32 (required output)

  const int SCAN_G = (N + 1023) / 1024;     // 49
  const int NB = (N + 127) / 128;           // 391 buckets

  // ---- workspace layout (all chunks 16B-aligned for N=50000, E=800000)
  char* wsp = (char*)d_ws;
  int* deg       = (int*)wsp;               wsp += (size_t)N * sizeof(int);
  int* row_start = (int*)wsp;               wsp += (size_t)N * sizeof(int);
  int* eidx      = (int*)wsp;               wsp += (size_t)E * sizeof(int);
  unsigned* pairs = (unsigned*)wsp;         wsp += (size_t)E * sizeof(unsigned);
  int* gcursor   = (int*)wsp;               wsp += 512 * sizeof(int);
  int* partials  = (int*)wsp;               wsp += 256 * sizeof(int);
  int* blk_off   = (int*)wsp;               wsp += 256 * sizeof(int);
  float* sum1    = (float*)wsp;             wsp += 128 * sizeof(float);
  float* sq1     = (float*)wsp;             wsp += 128 * sizeof(float);
  float* sum2    = (float*)wsp;             wsp += 64 * sizeof(float);
  float* sq2     = (float*)wsp;             wsp += 64 * sizeof(float);
  float* bufA    = (float*)wsp;             wsp += (size_t)N * 128 * sizeof(float);
  unsigned short* bfX = (unsigned short*)wsp; wsp += (size_t)N * 128 * 2;
  unsigned short* bfM = (unsigned short*)wsp; wsp += (size_t)N * 128 * 2;
  unsigned short* bfH = (unsigned short*)wsp; wsp += (size_t)N * 128 * 2;
  unsigned short* Wl1t = (unsigned short*)wsp; wsp += 128 * 128 * 2;
  unsigned short* Wr1t = (unsigned short*)wsp; wsp += 128 * 128 * 2;
  unsigned short* Wl2t = (unsigned short*)wsp; wsp += 128 * 128 * 2;
  unsigned short* Wr2t = (unsigned short*)wsp; wsp += 128 * 128 * 2;
  unsigned short* W1t  = (unsigned short*)wsp; wsp += 128 * 128 * 2;
  unsigned short* W2t  = (unsigned short*)wsp; wsp += 64 * 128 * 2;

  // ---- zero-init accumulated scratch (ws poisoned 0xAA each call)
  hipMemsetAsync(deg, 0, (size_t)N * sizeof(int), stream);
  hipMemsetAsync(sum1, 0, 384 * sizeof(float), stream);

  // ---- build CSR (dst -> list of src): deg -> scan -> bucket-scatter -> bucket-fill
  deg_kernel<<<(E + 255) / 256, 256, 0, stream>>>(dst, deg, E);
  scan_partial_kernel<<<SCAN_G, 256, 0, stream>>>(deg, partials, N);
  scan_offsets_kernel<<<1, 256, 0, stream>>>(partials, blk_off, SCAN_G);
  scan_scatter_kernel<<<SCAN_G, 256, 0, stream>>>(deg, blk_off, row_start, gcursor, N);
  csr_bucket_kernel<<<(E + CHUNK - 1) / CHUNK, 256, 0, stream>>>(src, dst, gcursor, pairs, E);
  csr_fill_kernel<<<NB, 256, 0, stream>>>(pairs, row_start, eidx, N, E);

  // ---- fused bf16 prep (xcast + all weight transposes)
  int xblocks = ((size_t)N * 128 + 255) / 256;
  prep_kernel<<<xblocks + 352, 256, 0, stream>>>(x, bfX,
      Wl1, Wr1, Wl2, Wr2, W1, W2, Wl1t, Wr1t, Wl2t, Wr2t, W1t, W2t, N, xblocks);

  int gemm_grid = (N + 63) / 64;

  // ---- layer 1: gather-mean(xb) -> bfM; sage MFMA -> h1 (fp32) + h1b (bfH)
  gather_kernel<<<(N + 3) / 4, 256, 0, stream>>>(bfX, eidx, row_start, deg, bfM, N);
  mfma_gemm_kernel<128, true, true, true, false><<<gemm_grid, 256, 0, stream>>>(
      bfM, Wl1t, bfX, Wr1t, bl1, h1, bfH, nullptr, nullptr, N);

  // ---- layer 2: gather-mean(h1b) -> bfX; sage MFMA -> h2 + h2b (bfM)
  gather_kernel<<<(N + 3) / 4, 256, 0, stream>>>(bfH, eidx, row_start, deg, bfX, N);
  mfma_gemm_kernel<128, true, true, true, false><<<gemm_grid, 256, 0, stream>>>(
      bfX, Wl2t, bfH, Wr2t, bl2, h2, bfM, nullptr, nullptr, N);

  // ---- MLP layer 1: y1 = h2b @ W1 + b1 (bufA) + fused col stats; BN+ReLU -> z1b (bfH)
  mfma_gemm_kernel<128, false, false, false, true><<<gemm_grid, 256, 0, stream>>>(
      bfM, W1t, nullptr, nullptr, b1, bufA, nullptr, sum1, sq1, N);
  bn_relu_kernel<<<((size_t)N * 128 + 255) / 256, 256, 0, stream>>>(
      bufA, N, sum1, sq1, g1, be1, bfH);

  // ---- MLP layer 2: y2 = z1b @ W2 + b2 (bufA reuse) + fused col stats
  mfma_gemm_kernel<64, false, false, false, true><<<gemm_grid, 256, 0, stream>>>(
      bfH, W2t, nullptr, nullptr, b2, bufA, nullptr, sum2, sq2, N);

  // ---- fused BN+ReLU+head: out = relu(bn(y2)) @ W3 + b3
  bn_head_kernel<<<(N + 3) / 4, 256, 0, stream>>>(
      bufA, sum2, sq2, g2, be2, W3, b3, out0, N);
}

// Round 6
// 401.941 us; speedup vs baseline: 7.6095x; 1.2310x over previous
//
#include <hip/hip_runtime.h>

#define BN_EPS 1e-5f

typedef short s8v __attribute__((ext_vector_type(8)));
typedef float f4v __attribute__((ext_vector_type(4)));

__device__ __forceinline__ unsigned short f2bf(float f) {
  union { float f; unsigned u; } v; v.f = f;
  unsigned r = v.u + 0x7FFF + ((v.u >> 16) & 1);
  return (unsigned short)(r >> 16);
}
__device__ __forceinline__ float bf2f(unsigned short u) {
  union { unsigned u; float f; } v; v.u = ((unsigned)u) << 16; return v.f;
}

// ---------------------------------------------------------------- degree histogram (int)
__global__ __launch_bounds__(256) void deg_kernel(const int* __restrict__ dst,
                                                  int* __restrict__ deg, int E) {
  int e = blockIdx.x * 256 + threadIdx.x;
  if (e < E) atomicAdd(&deg[dst[e]], 1);
}

// ------------------------------------------- scan pass 1: per-block (1024 elems) totals
__global__ __launch_bounds__(256) void scan_partial_kernel(const int* __restrict__ deg,
    int* __restrict__ partials, int N) {
  __shared__ int sh[256];
  int t = threadIdx.x;
  int base = blockIdx.x * 1024 + t * 4;
  int s = 0;
#pragma unroll
  for (int i = 0; i < 4; ++i) {
    int idx = base + i;
    if (idx < N) s += deg[idx];
  }
  sh[t] = s;
  __syncthreads();
  for (int d = 128; d > 0; d >>= 1) {
    if (t < d) sh[t] += sh[t + d];
    __syncthreads();
  }
  if (t == 0) partials[blockIdx.x] = sh[0];
}

// ------------------------------------------- scan pass 2: exclusive scan of partials
__global__ __launch_bounds__(256) void scan_offsets_kernel(const int* __restrict__ partials,
    int* __restrict__ blk_off, int G) {
  __shared__ int sh[256];
  int t = threadIdx.x;
  sh[t] = (t < G) ? partials[t] : 0;
  __syncthreads();
  for (int d = 1; d < 256; d <<= 1) {
    int v = (t >= d) ? sh[t - d] : 0;
    __syncthreads();
    sh[t] += v;
    __syncthreads();
  }
  if (t < G) blk_off[t] = (t == 0) ? 0 : sh[t - 1];
}

// ----- scan pass 3: block-local exclusive scan + offset -> row_start, bucket cursors
__global__ __launch_bounds__(256) void scan_scatter_kernel(const int* __restrict__ deg,
    const int* __restrict__ blk_off, int* __restrict__ row_start,
    int* __restrict__ gcursor, int N) {
  __shared__ int sh[256];
  int t = threadIdx.x;
  int base = blockIdx.x * 1024 + t * 4;
  int v[4];
#pragma unroll
  for (int i = 0; i < 4; ++i) v[i] = (base + i < N) ? deg[base + i] : 0;
  sh[t] = v[0] + v[1] + v[2] + v[3];
  __syncthreads();
  for (int d = 1; d < 256; d <<= 1) {
    int u = (t >= d) ? sh[t - d] : 0;
    __syncthreads();
    sh[t] += u;
    __syncthreads();
  }
  int off = blk_off[blockIdx.x] + ((t == 0) ? 0 : sh[t - 1]);
#pragma unroll
  for (int i = 0; i < 4; ++i) {
    int idx = base + i;
    if (idx < N) {
      row_start[idx] = off;
      if ((idx & 127) == 0) gcursor[idx >> 7] = off;  // pairs cursor = CSR bucket start
      off += v[i];
    }
  }
}

// ------------------- CSR phase A: LDS-staged bucket scatter (kills partial-line writes)
#define CHUNK 8192
#define NBMAX 512
__global__ __launch_bounds__(256) void csr_bucket_kernel(
    const int* __restrict__ src, const int* __restrict__ dst,
    int* __restrict__ gcursor, unsigned* __restrict__ pairs, int E) {
  __shared__ int h[NBMAX];
  __shared__ int off[NBMAX];
  __shared__ int cnt2[NBMAX];
  __shared__ int gadj[NBMAX];
  __shared__ unsigned pbuf[CHUNK];
  __shared__ unsigned short bidx[CHUNK];
  int t = threadIdx.x;
  int base = blockIdx.x * CHUNK;
  int cnt = min(CHUNK, E - base);
  for (int i = t; i < NBMAX; i += 256) { h[i] = 0; cnt2[i] = 0; }
  __syncthreads();
  for (int i = t; i < cnt; i += 256) atomicAdd(&h[dst[base + i] >> 7], 1);
  __syncthreads();
  off[t] = h[t]; off[t + 256] = h[t + 256];
  __syncthreads();
  for (int d = 1; d < 512; d <<= 1) {
    int v0 = (t >= d) ? off[t - d] : 0;
    int v1 = off[t + 256 - d];
    __syncthreads();
    off[t] += v0; off[t + 256] += v1;
    __syncthreads();
  }
  int e0 = off[t] - h[t];
  int e1 = off[t + 256] - h[t + 256];
  __syncthreads();
  off[t] = e0; off[t + 256] = e1;
  __syncthreads();
  for (int i = t; i < NBMAX; i += 256) {
    int c = h[i];
    if (c > 0) gadj[i] = atomicAdd(&gcursor[i], c) - off[i];
  }
  __syncthreads();
  for (int i = t; i < cnt; i += 256) {
    int s = src[base + i];
    int d = dst[base + i];
    int b = d >> 7;
    int p = off[b] + atomicAdd(&cnt2[b], 1);
    pbuf[p] = (unsigned)s | ((unsigned)d << 16);   // both < 2^16 (N=50000)
    bidx[p] = (unsigned short)b;
  }
  __syncthreads();
  for (int i = t; i < cnt; i += 256)
    pairs[gadj[bidx[i]] + i] = pbuf[i];
}

// ------------------- CSR phase B: one block per bucket, private eidx region, LDS cursors
__global__ __launch_bounds__(256) void csr_fill_kernel(
    const unsigned* __restrict__ pairs, const int* __restrict__ row_start,
    int* __restrict__ eidx, int N, int E) {
  __shared__ int cur[128];
  int b = blockIdx.x;
  int node0 = b << 7;
  int t = threadIdx.x;
  if (t < 128) {
    int node = node0 + t;
    cur[t] = (node < N) ? row_start[node] : 0;
  }
  __syncthreads();
  int pbeg = row_start[node0];
  int pend = (node0 + 128 < N) ? row_start[node0 + 128] : E;
  for (int i = pbeg + t; i < pend; i += 256) {
    unsigned p = pairs[i];
    int pos = atomicAdd(&cur[(int)(p >> 16) - node0], 1);
    eidx[pos] = (int)(p & 0xFFFFu);
  }
}

// --------------- fused prep: xcast (blocks [0,xblocks)) + 6 weight transposes
__global__ __launch_bounds__(256) void prep_kernel(
    const float* __restrict__ x, unsigned short* __restrict__ xb,
    const float* __restrict__ Wl1, const float* __restrict__ Wr1,
    const float* __restrict__ Wl2, const float* __restrict__ Wr2,
    const float* __restrict__ W1, const float* __restrict__ W2,
    unsigned short* __restrict__ Wl1t, unsigned short* __restrict__ Wr1t,
    unsigned short* __restrict__ Wl2t, unsigned short* __restrict__ Wr2t,
    unsigned short* __restrict__ W1t, unsigned short* __restrict__ W2t,
    int N, int xblocks) {
  int blk = blockIdx.x;
  if (blk < xblocks) {
    int t = blk * 256 + threadIdx.x;
    if (t < N * 128) {
      int col = t & 127;
      int n = t >> 7;
      xb[t] = (col < 100) ? f2bf(x[n * 100 + col]) : (unsigned short)0;
    }
    return;
  }
  int w = blk - xblocks;
  const float* W; unsigned short* Wt; int K, C, base;
  if (w < 64)       { W = Wl1; Wt = Wl1t; K = 100; C = 128; base = 0;   }
  else if (w < 128) { W = Wr1; Wt = Wr1t; K = 100; C = 128; base = 64;  }
  else if (w < 192) { W = Wl2; Wt = Wl2t; K = 128; C = 128; base = 128; }
  else if (w < 256) { W = Wr2; Wt = Wr2t; K = 128; C = 128; base = 192; }
  else if (w < 320) { W = W1;  Wt = W1t;  K = 128; C = 128; base = 256; }
  else              { W = W2;  Wt = W2t;  K = 128; C = 64;  base = 320; }
  int t = (w - base) * 256 + threadIdx.x;
  if (t >= C * 128) return;
  int c = t >> 7;
  int k = t & 127;
  Wt[t] = (k < K) ? f2bf(W[k * C + c]) : (unsigned short)0;
}

// ------------------------------------------ gather mean over bf16 rows (1 wave / node)
__global__ __launch_bounds__(256) void gather_kernel(
    const unsigned short* __restrict__ feat, const int* __restrict__ eidx,
    const int* __restrict__ row_start, const int* __restrict__ deg,
    unsigned short* __restrict__ mean_out, int N) {
  int wave = threadIdx.x >> 6;
  int lane = threadIdx.x & 63;
  int node = blockIdx.x * 4 + wave;
  if (node >= N) return;
  int beg = row_start[node];
  int d = deg[node];
  float a0 = 0.0f, a1 = 0.0f;
  for (int i0 = 0; i0 < d; i0 += 64) {
    int cnt = min(64, d - i0);
    int my = (lane < cnt) ? eidx[beg + i0 + lane] : 0;
    int j = 0;
    for (; j + 3 < cnt; j += 4) {
      int s0 = __shfl(my, j + 0);
      int s1 = __shfl(my, j + 1);
      int s2 = __shfl(my, j + 2);
      int s3 = __shfl(my, j + 3);
      unsigned v0 = ((const unsigned*)(feat + (size_t)s0 * 128))[lane];
      unsigned v1 = ((const unsigned*)(feat + (size_t)s1 * 128))[lane];
      unsigned v2 = ((const unsigned*)(feat + (size_t)s2 * 128))[lane];
      unsigned v3 = ((const unsigned*)(feat + (size_t)s3 * 128))[lane];
      a0 += bf2f((unsigned short)v0) + bf2f((unsigned short)v1)
          + bf2f((unsigned short)v2) + bf2f((unsigned short)v3);
      a1 += bf2f((unsigned short)(v0 >> 16)) + bf2f((unsigned short)(v1 >> 16))
          + bf2f((unsigned short)(v2 >> 16)) + bf2f((unsigned short)(v3 >> 16));
    }
    for (; j < cnt; ++j) {
      int s0 = __shfl(my, j);
      unsigned v0 = ((const unsigned*)(feat + (size_t)s0 * 128))[lane];
      a0 += bf2f((unsigned short)v0);
      a1 += bf2f((unsigned short)(v0 >> 16));
    }
  }
  float inv = 1.0f / fmaxf((float)d, 1.0f);
  unsigned o = (unsigned)f2bf(a0 * inv) | ((unsigned)f2bf(a1 * inv) << 16);
  ((unsigned*)(mean_out + (size_t)node * 128))[lane] = o;
}

// --------------------------------------------------------- MFMA GEMM (K padded to 128)
// STATS epilogue: block-level LDS reduction -> 1 atomic/col/block into 8-way-spread
// slots (sum[8][COLS]) -> 32x/16x less per-line atomic contention (R5: 87us stall).
template<int COLS, bool DUAL, bool RELU, bool BF16OUT, bool STATS>
__global__ __launch_bounds__(256) void mfma_gemm_kernel(
    const unsigned short* __restrict__ A1, const unsigned short* __restrict__ W1t,
    const unsigned short* __restrict__ A2, const unsigned short* __restrict__ W2t,
    const float* __restrict__ bias,
    float* __restrict__ outF, unsigned short* __restrict__ outB,
    float* __restrict__ sum, float* __restrict__ sq, int N) {
  const int CT = COLS / 16;
  __shared__ float lds[64][COLS + 4];
  __shared__ float red[STATS ? 512 : 1];
  int wave = threadIdx.x >> 6;
  int lane = threadIdx.x & 63;
  int quad = lane >> 4;
  int m = lane & 15;
  int n0 = blockIdx.x * 64 + wave * 16;
  bool valid = (n0 < N);

  f4v acc[CT];
#pragma unroll
  for (int ct = 0; ct < CT; ++ct) acc[ct] = (f4v){0.f, 0.f, 0.f, 0.f};

  if (valid) {
    const unsigned short* a1p = A1 + (size_t)(n0 + m) * 128 + quad * 8;
    const unsigned short* a2p = DUAL ? (A2 + (size_t)(n0 + m) * 128 + quad * 8) : nullptr;
#pragma unroll
    for (int k0 = 0; k0 < 128; k0 += 32) {
      s8v a1 = *(const s8v*)(a1p + k0);
      s8v a2;
      if (DUAL) a2 = *(const s8v*)(a2p + k0);
#pragma unroll
      for (int ct = 0; ct < CT; ++ct) {
        s8v b1 = *(const s8v*)(W1t + (size_t)(ct * 16 + m) * 128 + k0 + quad * 8);
        acc[ct] = __builtin_amdgcn_mfma_f32_16x16x32_bf16(a1, b1, acc[ct], 0, 0, 0);
        if (DUAL) {
          s8v b2 = *(const s8v*)(W2t + (size_t)(ct * 16 + m) * 128 + k0 + quad * 8);
          acc[ct] = __builtin_amdgcn_mfma_f32_16x16x32_bf16(a2, b2, acc[ct], 0, 0, 0);
        }
      }
    }
#pragma unroll
    for (int ct = 0; ct < CT; ++ct) {
      int col = ct * 16 + m;
      float b = bias[col];
#pragma unroll
      for (int r = 0; r < 4; ++r) {
        float v = acc[ct][r] + b;
        if (RELU) v = fmaxf(v, 0.0f);
        lds[wave * 16 + quad * 4 + r][col] = v;
      }
    }
  }
  __syncthreads();
  int blk = blockIdx.x * 64;
  float s = 0.0f, ss = 0.0f;
  for (int idx = threadIdx.x; idx < 64 * COLS; idx += 256) {
    int row = idx / COLS;
    int col = idx % COLS;   // constant per thread (256 % COLS == 0)
    int gr = blk + row;
    if (gr < N) {
      float v = lds[row][col];
      outF[(size_t)gr * COLS + col] = v;
      if (BF16OUT) outB[(size_t)gr * COLS + col] = f2bf(v);
      if (STATS) { s += v; ss += v * v; }
    }
  }
  if (STATS) {
    int t = threadIdx.x;
    red[t] = s;
    red[256 + t] = ss;
    __syncthreads();
    if (t < COLS) {
      float S = 0.0f, SS = 0.0f;
#pragma unroll
      for (int g = 0; g < 256 / COLS; ++g) {
        S  += red[t + g * COLS];
        SS += red[256 + t + g * COLS];
      }
      int slot = (blockIdx.x & 7) * COLS + t;
      atomicAdd(&sum[slot], S);
      atomicAdd(&sq[slot], SS);
    }
  }
}

// ------------------- BN (train) + ReLU: fp32 in -> bf16 out (C = 128, 8 stat slots)
__global__ __launch_bounds__(256) void bn_relu_kernel(const float* __restrict__ y,
    int N, const float* __restrict__ sum, const float* __restrict__ sumsq,
    const float* __restrict__ g, const float* __restrict__ be,
    unsigned short* __restrict__ yb) {
  int t = blockIdx.x * 256 + threadIdx.x;
  if (t >= N * 128) return;
  int col = t & 127;
  float S = 0.0f, SS = 0.0f;
#pragma unroll
  for (int k = 0; k < 8; ++k) { S += sum[k * 128 + col]; SS += sumsq[k * 128 + col]; }
  float invN = 1.0f / (float)N;
  float m = S * invN;
  float v = SS * invN - m * m;
  float val = (y[t] - m) * rsqrtf(v + BN_EPS) * g[col] + be[col];
  yb[t] = f2bf(fmaxf(val, 0.0f));
}

// ---------- fused BN(train)+ReLU (64 cols, 8 stat slots) + head dot: out = z2@W3+b3
__global__ __launch_bounds__(256) void bn_head_kernel(const float* __restrict__ y2,
    const float* __restrict__ sum, const float* __restrict__ sumsq,
    const float* __restrict__ g, const float* __restrict__ be,
    const float* __restrict__ W3, const float* __restrict__ b3,
    float* __restrict__ out, int N) {
  int wave = threadIdx.x >> 6;
  int lane = threadIdx.x & 63;
  int row = blockIdx.x * 4 + wave;
  if (row >= N) return;
  float S = 0.0f, SS = 0.0f;
#pragma unroll
  for (int k = 0; k < 8; ++k) { S += sum[k * 64 + lane]; SS += sumsq[k * 64 + lane]; }
  float invN = 1.0f / (float)N;
  float m = S * invN;
  float var = SS * invN - m * m;
  float val = (y2[(size_t)row * 64 + lane] - m) * rsqrtf(var + BN_EPS) * g[lane] + be[lane];
  val = fmaxf(val, 0.0f) * W3[lane];
#pragma unroll
  for (int off = 32; off > 0; off >>= 1) val += __shfl_down(val, off);
  if (lane == 0) out[row] = val + b3[0];
}

// ================================================================ launch
extern "C" void kernel_launch(void* const* d_in, const int* in_sizes, int n_in,
                              void* d_out, int out_size, void* d_ws, size_t ws_size,
                              hipStream_t stream) {
  const int F = 100, H = 128;
  const int N = in_sizes[0] / F;
  const int E = in_sizes[1] / 2;

  const float* x   = (const float*)d_in[0];
  const int* edge  = (const int*)d_in[1];
  const int* src   = edge;
  const int* dst   = edge + E;
  const float* Wl1 = (const float*)d_in[2];
  const float* bl1 = (const float*)d_in[3];
  const float* Wr1 = (const float*)d_in[4];
  const float* Wl2 = (const float*)d_in[5];
  const float* bl2 = (const float*)d_in[6];
  const float* Wr2 = (const float*)d_in[7];
  const float* W1  = (const float*)d_in[8];
  const float* b1  = (const float*)d_in[9];
  const float* g1  = (const float*)d_in[10];
  const float* be1 = (const float*)d_in[11];
  const float* W2  = (const float*)d_in[12];
  const float* b2  = (const float*)d_in[13];
  const float* g2  = (const float*)d_in[14];
  const float* be2 = (const float*)d_in[15];
  const float* W3  = (const float*)d_in[16];
  const float* b3  = (const float*)d_in[17];

  float* out0 = (float*)d_out;              // [N]
  float* h1   = out0 + N;                   // [N,128] fp32 (required output)
  float* h2   = h1 + (size_t)N * H;         // [N,128] fp32 (required output)

  const int SCAN_G = (N + 1023) / 1024;     // 49
  const int NB = (N + 127) / 128;           // 391 buckets

  // ---- workspace layout
  char* wsp = (char*)d_ws;
  int* deg       = (int*)wsp;               wsp += (size_t)N * sizeof(int);
  int* row_start = (int*)wsp;               wsp += (size_t)N * sizeof(int);
  int* eidx      = (int*)wsp;               wsp += (size_t)E * sizeof(int);
  unsigned* pairs = (unsigned*)wsp;         wsp += (size_t)E * sizeof(unsigned);
  int* gcursor   = (int*)wsp;               wsp += 512 * sizeof(int);
  int* partials  = (int*)wsp;               wsp += 256 * sizeof(int);
  int* blk_off   = (int*)wsp;               wsp += 256 * sizeof(int);
  float* sum1    = (float*)wsp;             wsp += 8 * 128 * sizeof(float);
  float* sq1     = (float*)wsp;             wsp += 8 * 128 * sizeof(float);
  float* sum2    = (float*)wsp;             wsp += 8 * 64 * sizeof(float);
  float* sq2     = (float*)wsp;             wsp += 8 * 64 * sizeof(float);
  float* bufA    = (float*)wsp;             wsp += (size_t)N * 128 * sizeof(float);
  unsigned short* bfX = (unsigned short*)wsp; wsp += (size_t)N * 128 * 2;
  unsigned short* bfM = (unsigned short*)wsp; wsp += (size_t)N * 128 * 2;
  unsigned short* bfH = (unsigned short*)wsp; wsp += (size_t)N * 128 * 2;
  unsigned short* Wl1t = (unsigned short*)wsp; wsp += 128 * 128 * 2;
  unsigned short* Wr1t = (unsigned short*)wsp; wsp += 128 * 128 * 2;
  unsigned short* Wl2t = (unsigned short*)wsp; wsp += 128 * 128 * 2;
  unsigned short* Wr2t = (unsigned short*)wsp; wsp += 128 * 128 * 2;
  unsigned short* W1t  = (unsigned short*)wsp; wsp += 128 * 128 * 2;
  unsigned short* W2t  = (unsigned short*)wsp; wsp += 64 * 128 * 2;

  // ---- zero-init accumulated scratch (ws poisoned 0xAA each call)
  hipMemsetAsync(deg, 0, (size_t)N * sizeof(int), stream);
  hipMemsetAsync(sum1, 0, (8 * 128 + 8 * 128 + 8 * 64 + 8 * 64) * sizeof(float), stream);

  // ---- build CSR (dst -> list of src): deg -> scan -> bucket-scatter -> bucket-fill
  deg_kernel<<<(E + 255) / 256, 256, 0, stream>>>(dst, deg, E);
  scan_partial_kernel<<<SCAN_G, 256, 0, stream>>>(deg, partials, N);
  scan_offsets_kernel<<<1, 256, 0, stream>>>(partials, blk_off, SCAN_G);
  scan_scatter_kernel<<<SCAN_G, 256, 0, stream>>>(deg, blk_off, row_start, gcursor, N);
  csr_bucket_kernel<<<(E + CHUNK - 1) / CHUNK, 256, 0, stream>>>(src, dst, gcursor, pairs, E);
  csr_fill_kernel<<<NB, 256, 0, stream>>>(pairs, row_start, eidx, N, E);

  // ---- fused bf16 prep (xcast + all weight transposes)
  int xblocks = ((size_t)N * 128 + 255) / 256;
  prep_kernel<<<xblocks + 352, 256, 0, stream>>>(x, bfX,
      Wl1, Wr1, Wl2, Wr2, W1, W2, Wl1t, Wr1t, Wl2t, Wr2t, W1t, W2t, N, xblocks);

  int gemm_grid = (N + 63) / 64;

  // ---- layer 1: gather-mean(xb) -> bfM; sage MFMA -> h1 (fp32) + h1b (bfH)
  gather_kernel<<<(N + 3) / 4, 256, 0, stream>>>(bfX, eidx, row_start, deg, bfM, N);
  mfma_gemm_kernel<128, true, true, true, false><<<gemm_grid, 256, 0, stream>>>(
      bfM, Wl1t, bfX, Wr1t, bl1, h1, bfH, nullptr, nullptr, N);

  // ---- layer 2: gather-mean(h1b) -> bfX; sage MFMA -> h2 + h2b (bfM)
  gather_kernel<<<(N + 3) / 4, 256, 0, stream>>>(bfH, eidx, row_start, deg, bfX, N);
  mfma_gemm_kernel<128, true, true, true, false><<<gemm_grid, 256, 0, stream>>>(
      bfX, Wl2t, bfH, Wr2t, bl2, h2, bfM, nullptr, nullptr, N);

  // ---- MLP layer 1: y1 = h2b @ W1 + b1 (bufA) + fused col stats; BN+ReLU -> z1b (bfH)
  mfma_gemm_kernel<128, false, false, false, true><<<gemm_grid, 256, 0, stream>>>(
      bfM, W1t, nullptr, nullptr, b1, bufA, nullptr, sum1, sq1, N);
  bn_relu_kernel<<<((size_t)N * 128 + 255) / 256, 256, 0, stream>>>(
      bufA, N, sum1, sq1, g1, be1, bfH);

  // ---- MLP layer 2: y2 = z1b @ W2 + b2 (bufA reuse) + fused col stats
  mfma_gemm_kernel<64, false, false, false, true><<<gemm_grid, 256, 0, stream>>>(
      bfH, W2t, nullptr, nullptr, b2, bufA, nullptr, sum2, sq2, N);

  // ---- fused BN+ReLU+head: out = relu(bn(y2)) @ W3 + b3
  bn_head_kernel<<<(N + 3) / 4, 256, 0, stream>>>(
      bufA, sum2, sq2, g2, be2, W3, b3, out0, N);
}